// Round 1
// baseline (924.862 us; speedup 1.0000x reference)
//
#include <hip/hip_runtime.h>
#include <hip/hip_bf16.h>
#include <math.h>

#define NN 20000
#define NE 320000
#define DD 256
#define NH 8
#define KK 32
#define NR 5
#define NC 16

typedef unsigned short u16;
typedef unsigned int u32;

__device__ __forceinline__ float bf2f(u16 v){ return __uint_as_float(((u32)v)<<16); }
__device__ __forceinline__ u16 f2bf(float f){
  u32 u = __float_as_uint(f);
  return (u16)((u + 0x7FFFu + ((u>>16)&1u)) >> 16);
}

// ---------------- node bucketing by type (for typed GEMMs) ----------------
__global__ void k_nb_count(const int* __restrict__ ntype, int* __restrict__ cnt){
  int n = blockIdx.x*256 + threadIdx.x;
  if(n < NN) atomicAdd(&cnt[ntype[n]], 1);
}
__global__ void k_nb_off(const int* __restrict__ cnt, int* __restrict__ boff){
  int a = (cnt[0]+31)&~31;
  int b = (cnt[1]+31)&~31;
  boff[0]=0; boff[1]=a; boff[2]=a+b;
}
__global__ void k_nb_scatter(const int* __restrict__ ntype, const int* __restrict__ boff,
                             int* __restrict__ bcur, int* __restrict__ perm){
  int n = blockIdx.x*256 + threadIdx.x;
  if(n < NN){
    int t = ntype[n];
    int pos = boff[t] + atomicAdd(&bcur[t], 1);
    perm[pos] = n;
  }
}

// ---------------- CSR by dst ----------------
__global__ void k_deg(const int* __restrict__ ei, int* __restrict__ deg){
  int e = blockIdx.x*256 + threadIdx.x;
  if(e < NE) atomicAdd(&deg[ei[NE + e]], 1);
}
__global__ void k_scan(const int* __restrict__ deg, int* __restrict__ row_off){
  __shared__ int sums[1024];
  int t = threadIdx.x;
  const int CH = 20;                 // 1024*20 >= NN
  int local[CH];
  int s = 0;
  #pragma unroll
  for(int j=0;j<CH;j++){
    int i = t*CH + j;
    local[j] = s;
    s += (i < NN) ? deg[i] : 0;
  }
  sums[t] = s;
  __syncthreads();
  for(int off=1; off<1024; off<<=1){
    int v = (t>=off) ? sums[t-off] : 0;
    __syncthreads();
    if(t>=off) sums[t] += v;
    __syncthreads();
  }
  int base = (t==0) ? 0 : sums[t-1];
  #pragma unroll
  for(int j=0;j<CH;j++){
    int i = t*CH + j;
    if(i < NN) row_off[i] = base + local[j];
  }
  if(t==1023) row_off[NN] = sums[1023];
}
__global__ void k_escatter(const int* __restrict__ ei, const int* __restrict__ etype,
                           const int* __restrict__ row_off, int* __restrict__ cursor,
                           int* __restrict__ packed){
  int e = blockIdx.x*256 + threadIdx.x;
  if(e < NE){
    int dst = ei[NE+e];
    int pos = row_off[dst] + atomicAdd(&cursor[dst],1);
    packed[pos] = ei[e] | (etype[e] << 20);   // src < 2^20, r in bits 20..22
  }
}

// ---------------- typed K/Q/V projections: 32-node tile GEMM ----------------
__global__ __launch_bounds__(256) void k_proj(
    const float* __restrict__ x, const int* __restrict__ perm, const int* __restrict__ boff,
    const float* __restrict__ Wk, const float* __restrict__ bk,
    const float* __restrict__ Wq, const float* __restrict__ bq,
    const float* __restrict__ Wv, const float* __restrict__ bv,
    u16* __restrict__ Kn, float* __restrict__ Qn, u16* __restrict__ Vn)
{
  __shared__ float xs[32*DD];
  __shared__ int gids[32];
  int tid = threadIdx.x;
  int ts = blockIdx.x*32;
  int t = (ts >= boff[2]) ? 2 : (ts >= boff[1]) ? 1 : 0;   // boff 32-aligned -> no straddle
  if(tid < 32) gids[tid] = perm[ts + tid];
  __syncthreads();
  #pragma unroll
  for(int it=0; it<8; it++){
    int f4 = tid + it*256;
    int row = f4 >> 6, c4 = f4 & 63;
    int g = gids[row];
    float4 v = make_float4(0.f,0.f,0.f,0.f);
    if(g >= 0) v = ((const float4*)(x + (size_t)g*DD))[c4];
    ((float4*)xs)[f4] = v;
  }
  __syncthreads();
  float accK[32], accQ[32], accV[32];
  #pragma unroll
  for(int n=0;n<32;n++){ accK[n]=0.f; accQ[n]=0.f; accV[n]=0.f; }
  const float* wk = Wk + t*65536 + tid;
  const float* wq = Wq + t*65536 + tid;
  const float* wv = Wv + t*65536 + tid;
  for(int i=0;i<DD;i+=4){
    float k0=wk[(i+0)*DD], k1=wk[(i+1)*DD], k2=wk[(i+2)*DD], k3=wk[(i+3)*DD];
    float q0=wq[(i+0)*DD], q1=wq[(i+1)*DD], q2=wq[(i+2)*DD], q3=wq[(i+3)*DD];
    float v0=wv[(i+0)*DD], v1=wv[(i+1)*DD], v2=wv[(i+2)*DD], v3=wv[(i+3)*DD];
    #pragma unroll
    for(int n=0;n<32;n++){
      float4 xv = ((const float4*)(xs + n*DD))[i>>2];
      accK[n] += xv.x*k0 + xv.y*k1 + xv.z*k2 + xv.w*k3;
      accQ[n] += xv.x*q0 + xv.y*q1 + xv.z*q2 + xv.w*q3;
      accV[n] += xv.x*v0 + xv.y*v1 + xv.z*v2 + xv.w*v3;
    }
  }
  float bkv = bk[t*DD+tid], bqv = bq[t*DD+tid], bvv = bv[t*DD+tid];
  for(int n=0;n<32;n++){
    int g = gids[n];
    if(g >= 0){
      Kn[(size_t)g*DD + tid] = f2bf(accK[n] + bkv);
      Qn[(size_t)g*DD + tid] = accQ[n] + bqv;
      Vn[(size_t)g*DD + tid] = f2bf(accV[n] + bvv);
    }
  }
}

// ---------------- QA[n,r,h,k] = (prior/sqrtK) * sum_l A[r,h,k,l]*Qn[n,h,l] ----------------
__global__ __launch_bounds__(256) void k_qa(
    const float* __restrict__ Qn, const float* __restrict__ rel_att,
    const float* __restrict__ rel_prior, u16* __restrict__ QA)
{
  __shared__ float At[NH*KK*33];    // [h][l][k], padded to kill bank conflicts
  __shared__ float qs[16*DD];
  int tid = threadIdx.x;
  int r = blockIdx.y;
  int n0 = blockIdx.x * 16;
  const float* A = rel_att + r*NH*KK*KK;
  #pragma unroll
  for(int it=0; it<32; it++){
    int idx = tid + it*256;
    int h = idx >> 10, k = (idx >> 5) & 31, l = idx & 31;
    At[(h*KK + l)*33 + k] = A[idx];
  }
  #pragma unroll
  for(int it=0; it<4; it++){
    int f4 = tid + it*256;
    ((float4*)qs)[f4] = ((const float4*)(Qn + (size_t)n0*DD))[f4];
  }
  __syncthreads();
  int h = tid >> 5, k = tid & 31;
  float areg[KK];
  #pragma unroll
  for(int l=0;l<KK;l++) areg[l] = At[(h*KK + l)*33 + k];
  float scale = rel_prior[r*NH + h] * 0.17677669529663687f;  // 1/sqrt(32)
  for(int n=0;n<16;n++){
    float s = 0.f;
    #pragma unroll
    for(int l4=0;l4<8;l4++){
      float4 q = ((const float4*)(qs + n*DD + h*KK))[l4];
      s += areg[l4*4+0]*q.x + areg[l4*4+1]*q.y + areg[l4*4+2]*q.z + areg[l4*4+3]*q.w;
    }
    QA[((size_t)(n0+n)*NR + r)*DD + tid] = f2bf(s*scale);
  }
}

// ---------------- fused per-node softmax + aggregation (wave per node, no atomics) --------
__global__ __launch_bounds__(256) void k_edge(
    const u16* __restrict__ Kn, const u16* __restrict__ Vn, const u16* __restrict__ QA,
    const int* __restrict__ row_off, const int* __restrict__ packed,
    u16* __restrict__ aggrV)
{
  int lane = threadIdx.x & 63;
  int n = blockIdx.x*4 + (threadIdx.x >> 6);
  if(n >= NN) return;
  int off = lane*4;                  // = h*32 + j*4 with h=lane>>3
  float4 qa0,qa1,qa2,qa3,qa4;
  {
    const u16* qp = QA + (size_t)n*NR*DD + off;
    ushort4 q;
    q = *(const ushort4*)(qp + 0*DD); qa0 = make_float4(bf2f(q.x),bf2f(q.y),bf2f(q.z),bf2f(q.w));
    q = *(const ushort4*)(qp + 1*DD); qa1 = make_float4(bf2f(q.x),bf2f(q.y),bf2f(q.z),bf2f(q.w));
    q = *(const ushort4*)(qp + 2*DD); qa2 = make_float4(bf2f(q.x),bf2f(q.y),bf2f(q.z),bf2f(q.w));
    q = *(const ushort4*)(qp + 3*DD); qa3 = make_float4(bf2f(q.x),bf2f(q.y),bf2f(q.z),bf2f(q.w));
    q = *(const ushort4*)(qp + 4*DD); qa4 = make_float4(bf2f(q.x),bf2f(q.y),bf2f(q.z),bf2f(q.w));
  }
  float4 a0=make_float4(0,0,0,0), a1=a0, a2=a0, a3=a0, a4=a0;
  float s = 0.f;
  int e0 = row_off[n], e1 = row_off[n+1];
  for(int e=e0; e<e1; e++){
    int pk = packed[e];              // wave-uniform
    int src = pk & 0xFFFFF;
    int r = pk >> 20;
    ushort4 ku = *(const ushort4*)(Kn + (size_t)src*DD + off);
    ushort4 vu = *(const ushort4*)(Vn + (size_t)src*DD + off);
    float4 kv = make_float4(bf2f(ku.x),bf2f(ku.y),bf2f(ku.z),bf2f(ku.w));
    float4 vv = make_float4(bf2f(vu.x),bf2f(vu.y),bf2f(vu.z),bf2f(vu.w));
    float4 q;
    switch(r){ case 0: q=qa0; break; case 1: q=qa1; break; case 2: q=qa2; break;
               case 3: q=qa3; break; default: q=qa4; }
    float d = kv.x*q.x + kv.y*q.y + kv.z*q.z + kv.w*q.w;
    d += __shfl_xor(d, 1);           // butterfly within the 8-lane head group
    d += __shfl_xor(d, 2);
    d += __shfl_xor(d, 4);
    float p = __expf(d);             // no max-subtract: logits ~O(1), fp32-safe
    s += p;
    switch(r){
      case 0: a0.x+=p*vv.x; a0.y+=p*vv.y; a0.z+=p*vv.z; a0.w+=p*vv.w; break;
      case 1: a1.x+=p*vv.x; a1.y+=p*vv.y; a1.z+=p*vv.z; a1.w+=p*vv.w; break;
      case 2: a2.x+=p*vv.x; a2.y+=p*vv.y; a2.z+=p*vv.z; a2.w+=p*vv.w; break;
      case 3: a3.x+=p*vv.x; a3.y+=p*vv.y; a3.z+=p*vv.z; a3.w+=p*vv.w; break;
      default:a4.x+=p*vv.x; a4.y+=p*vv.y; a4.z+=p*vv.z; a4.w+=p*vv.w; break;
    }
  }
  float inv = (s > 0.f) ? (1.f/s) : 0.f;
  u16* op = aggrV + (size_t)n*NR*DD + off;
  #define ST(ptr, a) { ushort4 o; o.x=f2bf((a).x*inv); o.y=f2bf((a).y*inv); \
                       o.z=f2bf((a).z*inv); o.w=f2bf((a).w*inv); *(ushort4*)(ptr)=o; }
  ST(op + 0*DD, a0); ST(op + 1*DD, a1); ST(op + 2*DD, a2); ST(op + 3*DD, a3); ST(op + 4*DD, a4);
  #undef ST
}

// ---------------- apply rel_msg per (node, r), sum over r, ELU ----------------
__global__ __launch_bounds__(256) void k_msg(
    const u16* __restrict__ aggrV, const float* __restrict__ rel_msg,
    float* __restrict__ h1)
{
  __shared__ float Ms[NH*KK*KK];     // [h][k][l]
  __shared__ ushort4 Vs[32*64];      // 32 nodes x 256 bf16
  int tid = threadIdx.x;
  int n0 = blockIdx.x*32;
  int h = tid >> 5, l = tid & 31;
  float acc[32];
  #pragma unroll
  for(int n=0;n<32;n++) acc[n]=0.f;
  for(int r=0;r<NR;r++){
    #pragma unroll
    for(int it=0; it<32; it++){
      int idx = tid + it*256;
      Ms[idx] = rel_msg[r*8192 + idx];
    }
    #pragma unroll
    for(int it=0; it<8; it++){
      int f4 = tid + it*256;
      int row = f4 >> 6, c4 = f4 & 63;
      Vs[f4] = ((const ushort4*)(aggrV + ((size_t)(n0+row)*NR + r)*DD))[c4];
    }
    __syncthreads();
    float mreg[KK];
    #pragma unroll
    for(int k=0;k<KK;k++) mreg[k] = Ms[h*1024 + k*KK + l];
    for(int n=0;n<32;n++){
      #pragma unroll
      for(int k4=0;k4<8;k4++){
        ushort4 v = Vs[n*64 + h*8 + k4];
        acc[n] += mreg[k4*4+0]*bf2f(v.x) + mreg[k4*4+1]*bf2f(v.y)
                + mreg[k4*4+2]*bf2f(v.z) + mreg[k4*4+3]*bf2f(v.w);
      }
    }
    __syncthreads();
  }
  for(int n=0;n<32;n++){
    float v = acc[n];
    v = (v > 0.f) ? v : expm1f(v);
    h1[(size_t)(n0+n)*DD + tid] = v;
  }
}

// ---------------- typed Wa + residual + classifier + log_softmax ----------------
__global__ __launch_bounds__(256) void k_out(
    const float* __restrict__ h1, const float* __restrict__ x,
    const int* __restrict__ perm, const int* __restrict__ boff,
    const float* __restrict__ Wa, const float* __restrict__ ba,
    const float* __restrict__ Wo, const float* __restrict__ bo,
    float* __restrict__ out)
{
  __shared__ float hs[32*DD];
  __shared__ float wo[DD*NC];
  __shared__ float cls[32*NC];
  __shared__ int gids[32];
  int tid = threadIdx.x;
  int ts = blockIdx.x*32;
  int t = (ts >= boff[2]) ? 2 : (ts >= boff[1]) ? 1 : 0;
  if(tid < 32) gids[tid] = perm[ts + tid];
  #pragma unroll
  for(int it=0; it<16; it++) wo[tid + it*256] = Wo[tid + it*256];
  __syncthreads();
  #pragma unroll
  for(int it=0; it<8; it++){
    int f4 = tid + it*256;
    int row = f4 >> 6, c4 = f4 & 63;
    int g = gids[row];
    float4 v = make_float4(0.f,0.f,0.f,0.f);
    if(g >= 0) v = ((const float4*)(h1 + (size_t)g*DD))[c4];
    ((float4*)hs)[f4] = v;
  }
  __syncthreads();
  float acc[32];
  #pragma unroll
  for(int n=0;n<32;n++) acc[n]=0.f;
  const float* wa = Wa + t*65536 + tid;
  for(int i=0;i<DD;i+=4){
    float w0=wa[(i+0)*DD], w1=wa[(i+1)*DD], w2=wa[(i+2)*DD], w3=wa[(i+3)*DD];
    #pragma unroll
    for(int n=0;n<32;n++){
      float4 xv = ((const float4*)(hs + n*DD))[i>>2];
      acc[n] += xv.x*w0 + xv.y*w1 + xv.z*w2 + xv.w*w3;
    }
  }
  float bav = ba[t*DD + tid];
  float h2v[32];
  for(int n=0;n<32;n++){
    int g = gids[n];
    float xr = (g>=0) ? x[(size_t)g*DD + tid] : 0.f;
    h2v[n] = acc[n] + bav + xr;
  }
  __syncthreads();
  for(int n=0;n<32;n++) hs[n*DD + tid] = h2v[n];
  __syncthreads();
  {
    int n = tid >> 3, q = tid & 7;
    int c0 = q*2;
    float s0 = bo[c0], s1 = bo[c0+1];
    for(int i=0;i<DD;i++){
      float hv = hs[n*DD + i];
      s0 += hv * wo[i*NC + c0];
      s1 += hv * wo[i*NC + c0 + 1];
    }
    cls[n*NC + c0] = s0;
    cls[n*NC + c0 + 1] = s1;
  }
  __syncthreads();
  if(tid < 32){
    int g = gids[tid];
    if(g >= 0){
      float m = -1e30f;
      #pragma unroll
      for(int c=0;c<NC;c++) m = fmaxf(m, cls[tid*NC + c]);
      float sum = 0.f;
      #pragma unroll
      for(int c=0;c<NC;c++) sum += __expf(cls[tid*NC + c] - m);
      float lse = m + __logf(sum);
      #pragma unroll
      for(int c=0;c<NC;c++) out[(size_t)g*NC + c] = cls[tid*NC + c] - lse;
    }
  }
}

extern "C" void kernel_launch(void* const* d_in, const int* in_sizes, int n_in,
                              void* d_out, int out_size, void* d_ws, size_t ws_size,
                              hipStream_t stream)
{
  const float* x     = (const float*)d_in[0];
  const int*   ei    = (const int*)d_in[1];
  const int*   ntype = (const int*)d_in[2];
  const int*   etype = (const int*)d_in[3];
  const float* Wk    = (const float*)d_in[4];
  const float* bk    = (const float*)d_in[5];
  const float* Wq    = (const float*)d_in[6];
  const float* bq    = (const float*)d_in[7];
  const float* Wv    = (const float*)d_in[8];
  const float* bv    = (const float*)d_in[9];
  const float* Wa    = (const float*)d_in[10];
  const float* ba    = (const float*)d_in[11];
  const float* prior = (const float*)d_in[12];
  const float* ratt  = (const float*)d_in[13];
  const float* rmsg  = (const float*)d_in[14];
  const float* Wo    = (const float*)d_in[15];
  const float* bo    = (const float*)d_in[16];
  float* out = (float*)d_out;

  char* ws = (char*)d_ws;
  int* iw      = (int*)ws;
  int* cnt     = iw + 0;
  int* bcur    = iw + 4;
  int* boff    = iw + 8;
  int* deg     = iw + 16;
  int* cursor  = iw + 16 + NN;
  int* row_off = iw + 16 + 2*NN;          // NN+1 entries
  int* perm    = iw + 60032;              // 628*32 = 20096 entries
  int* packed  = iw + 80128;              // NE entries; ends at int 400128

  size_t fb = 1600512;                    // bytes (400128 ints), 256-aligned
  float* Qn    = (float*)(ws + fb); fb += 4ull*NN*DD;
  float* h1    = (float*)(ws + fb); fb += 4ull*NN*DD;
  u16*   Kn    = (u16*)(ws + fb);   fb += 2ull*NN*DD;
  u16*   Vn    = (u16*)(ws + fb);   fb += 2ull*NN*DD;
  u16*   QA    = (u16*)(ws + fb);   fb += 2ull*NN*NR*DD;
  u16*   aggrV = (u16*)(ws + fb);   fb += 2ull*NN*NR*DD;
  // total ws need: ~165.5 MB

  hipMemsetAsync(iw, 0, (size_t)(16 + 2*NN)*sizeof(int), stream);      // cnt,bcur,boff,deg,cursor
  hipMemsetAsync(perm, 0xFF, (size_t)20096*sizeof(int), stream);       // perm = -1

  k_nb_count  <<<79, 256, 0, stream>>>(ntype, cnt);
  k_nb_off    <<<1, 1, 0, stream>>>(cnt, boff);
  k_nb_scatter<<<79, 256, 0, stream>>>(ntype, boff, bcur, perm);
  k_deg       <<<1250, 256, 0, stream>>>(ei, deg);
  k_scan      <<<1, 1024, 0, stream>>>(deg, row_off);
  k_escatter  <<<1250, 256, 0, stream>>>(ei, etype, row_off, cursor, packed);
  k_proj      <<<628, 256, 0, stream>>>(x, perm, boff, Wk, bk, Wq, bq, Wv, bv, Kn, Qn, Vn);
  k_qa        <<<dim3(1250,5), 256, 0, stream>>>(Qn, ratt, prior, QA);
  k_edge      <<<5000, 256, 0, stream>>>(Kn, Vn, QA, row_off, packed, aggrV);
  k_msg       <<<625, 256, 0, stream>>>(aggrV, rmsg, h1);
  k_out       <<<628, 256, 0, stream>>>(h1, x, perm, boff, Wa, ba, Wo, bo, out);
}

// Round 2
// 838.671 us; speedup vs baseline: 1.1028x; 1.1028x over previous
//
#include <hip/hip_runtime.h>
#include <hip/hip_bf16.h>
#include <math.h>

#define NN 20000
#define NE 320000
#define DD 256
#define NH 8
#define KK 32
#define NR 5
#define NC 16

typedef unsigned short u16;
typedef unsigned int u32;
typedef __attribute__((ext_vector_type(8))) short bf16x8;
typedef __attribute__((ext_vector_type(4))) float f32x4;

__device__ __forceinline__ float bf2f(u16 v){ return __uint_as_float(((u32)v)<<16); }
__device__ __forceinline__ u16 f2bf(float f){
  u32 u = __float_as_uint(f);
  return (u16)((u + 0x7FFFu + ((u>>16)&1u)) >> 16);
}

// ---------------- node bucketing by type (for typed GEMMs) ----------------
__global__ void k_nb_count(const int* __restrict__ ntype, int* __restrict__ cnt){
  int n = blockIdx.x*256 + threadIdx.x;
  if(n < NN) atomicAdd(&cnt[ntype[n]], 1);
}
__global__ void k_nb_off(const int* __restrict__ cnt, int* __restrict__ boff){
  int a = (cnt[0]+31)&~31;
  int b = (cnt[1]+31)&~31;
  boff[0]=0; boff[1]=a; boff[2]=a+b;
}
__global__ void k_nb_scatter(const int* __restrict__ ntype, const int* __restrict__ boff,
                             int* __restrict__ bcur, int* __restrict__ perm){
  int n = blockIdx.x*256 + threadIdx.x;
  if(n < NN){
    int t = ntype[n];
    int pos = boff[t] + atomicAdd(&bcur[t], 1);
    perm[pos] = n;
  }
}

// ---------------- CSR by dst ----------------
__global__ void k_deg(const int* __restrict__ ei, int* __restrict__ deg){
  int e = blockIdx.x*256 + threadIdx.x;
  if(e < NE) atomicAdd(&deg[ei[NE + e]], 1);
}
__global__ void k_scan(const int* __restrict__ deg, int* __restrict__ row_off){
  __shared__ int sums[1024];
  int t = threadIdx.x;
  const int CH = 20;                 // 1024*20 >= NN
  int local[CH];
  int s = 0;
  #pragma unroll
  for(int j=0;j<CH;j++){
    int i = t*CH + j;
    local[j] = s;
    s += (i < NN) ? deg[i] : 0;
  }
  sums[t] = s;
  __syncthreads();
  for(int off=1; off<1024; off<<=1){
    int v = (t>=off) ? sums[t-off] : 0;
    __syncthreads();
    if(t>=off) sums[t] += v;
    __syncthreads();
  }
  int base = (t==0) ? 0 : sums[t-1];
  #pragma unroll
  for(int j=0;j<CH;j++){
    int i = t*CH + j;
    if(i < NN) row_off[i] = base + local[j];
  }
  if(t==1023) row_off[NN] = sums[1023];
}
__global__ void k_escatter(const int* __restrict__ ei, const int* __restrict__ etype,
                           const int* __restrict__ row_off, int* __restrict__ cursor,
                           int* __restrict__ packed){
  int e = blockIdx.x*256 + threadIdx.x;
  if(e < NE){
    int dst = ei[NE+e];
    int pos = row_off[dst] + atomicAdd(&cursor[dst],1);
    packed[pos] = ei[e] | (etype[e] << 20);   // src < 2^20, r in bits 20..22
  }
}

// ---------------- prep: cast x -> bf16 ----------------
__global__ void k_castx(const float* __restrict__ x, u16* __restrict__ xb){
  int i = blockIdx.x*256 + threadIdx.x;     // 8 floats per thread; 2500 blocks
  float4 v0 = ((const float4*)x)[i*2+0];
  float4 v1 = ((const float4*)x)[i*2+1];
  uint4 o;
  o.x = (u32)f2bf(v0.x) | ((u32)f2bf(v0.y)<<16);
  o.y = (u32)f2bf(v0.z) | ((u32)f2bf(v0.w)<<16);
  o.z = (u32)f2bf(v1.x) | ((u32)f2bf(v1.y)<<16);
  o.w = (u32)f2bf(v1.z) | ((u32)f2bf(v1.w)<<16);
  ((uint4*)xb)[i] = o;
}

// ---------------- prep: transpose + cast Wk/Wq/Wv -> bf16 [t][out][in] ----------------
__global__ __launch_bounds__(256) void k_castw(
  const float* __restrict__ Wk, const float* __restrict__ Wq, const float* __restrict__ Wv,
  u16* __restrict__ Wtk, u16* __restrict__ Wtq, u16* __restrict__ Wtv)
{
  __shared__ float tile[32][33];
  int z = blockIdx.z;                       // 0..8: tensor*3 + t
  int tensor = z/3, t = z%3;
  const float* W = (tensor==0) ? Wk : (tensor==1) ? Wq : Wv;
  u16* O = (tensor==0) ? Wtk : (tensor==1) ? Wtq : Wtv;
  int i0 = blockIdx.x*32, j0 = blockIdx.y*32;
  int rr = threadIdx.x>>5, cc = threadIdx.x&31;
  #pragma unroll
  for(int p=0;p<4;p++)
    tile[rr+p*8][cc] = W[t*65536 + (i0+rr+p*8)*256 + j0+cc];
  __syncthreads();
  #pragma unroll
  for(int p=0;p<4;p++)
    O[t*65536 + (j0+rr+p*8)*256 + i0+cc] = f2bf(tile[cc][rr+p*8]);
}

// ---------------- typed K/Q/V projections via MFMA 16x16x32 bf16 ----------------
// block = 256 threads (4 waves); tile = 32 nodes x 256 out-features; K=256.
// wave w covers out cols [w*64, w*64+64) as 4 n-tiles of 16.
__global__ __launch_bounds__(256) void k_proj(
    const u16* __restrict__ xb, const int* __restrict__ perm, const int* __restrict__ boff,
    const u16* __restrict__ Wtk, const u16* __restrict__ Wtq, const u16* __restrict__ Wtv,
    const float* __restrict__ bk, const float* __restrict__ bq, const float* __restrict__ bv,
    u16* __restrict__ Kn, float* __restrict__ Qn, u16* __restrict__ Vn)
{
  __shared__ u16 xs[32*DD];
  __shared__ int gids[32];
  int tid = threadIdx.x;
  int ts = blockIdx.x*32;
  int t = (ts >= boff[2]) ? 2 : (ts >= boff[1]) ? 1 : 0;   // boff 32-aligned
  if(tid < 32) gids[tid] = perm[ts + tid];
  __syncthreads();
  #pragma unroll
  for(int it=0; it<4; it++){
    int q = tid + it*256;
    int row = q >> 5, c = q & 31;
    int g = gids[row];
    uint4 v = make_uint4(0,0,0,0);
    if(g >= 0) v = ((const uint4*)(xb + (size_t)g*DD))[c];
    ((uint4*)xs)[q] = v;
  }
  __syncthreads();
  int lane = tid & 63;
  int w = tid >> 6;
  int quad = lane >> 4;
  int l16 = lane & 15;
  f32x4 accK[2][4], accQ[2][4], accV[2][4];
  #pragma unroll
  for(int mt=0;mt<2;mt++)
    #pragma unroll
    for(int nt=0;nt<4;nt++){
      accK[mt][nt]=(f32x4)(0.f); accQ[mt][nt]=(f32x4)(0.f); accV[mt][nt]=(f32x4)(0.f);
    }
  const u16* wkp = Wtk + (size_t)t*65536;
  const u16* wqp = Wtq + (size_t)t*65536;
  const u16* wvp = Wtv + (size_t)t*65536;
  #pragma unroll
  for(int kk=0; kk<8; kk++){
    int kb = kk*32 + quad*8;
    bf16x8 a0 = *(const bf16x8*)(xs + l16*DD + kb);
    bf16x8 a1 = *(const bf16x8*)(xs + (16+l16)*DD + kb);
    #pragma unroll
    for(int nt=0; nt<4; nt++){
      int n = w*64 + nt*16 + l16;
      bf16x8 bK = *(const bf16x8*)(wkp + (size_t)n*DD + kb);
      bf16x8 bQ = *(const bf16x8*)(wqp + (size_t)n*DD + kb);
      bf16x8 bV = *(const bf16x8*)(wvp + (size_t)n*DD + kb);
      accK[0][nt] = __builtin_amdgcn_mfma_f32_16x16x32_bf16(a0, bK, accK[0][nt], 0,0,0);
      accK[1][nt] = __builtin_amdgcn_mfma_f32_16x16x32_bf16(a1, bK, accK[1][nt], 0,0,0);
      accQ[0][nt] = __builtin_amdgcn_mfma_f32_16x16x32_bf16(a0, bQ, accQ[0][nt], 0,0,0);
      accQ[1][nt] = __builtin_amdgcn_mfma_f32_16x16x32_bf16(a1, bQ, accQ[1][nt], 0,0,0);
      accV[0][nt] = __builtin_amdgcn_mfma_f32_16x16x32_bf16(a0, bV, accV[0][nt], 0,0,0);
      accV[1][nt] = __builtin_amdgcn_mfma_f32_16x16x32_bf16(a1, bV, accV[1][nt], 0,0,0);
    }
  }
  #pragma unroll
  for(int nt=0; nt<4; nt++){
    int colg = w*64 + nt*16 + l16;
    float bkv = bk[t*DD+colg], bqv = bq[t*DD+colg], bvv = bv[t*DD+colg];
    #pragma unroll
    for(int mt=0; mt<2; mt++){
      #pragma unroll
      for(int reg=0; reg<4; reg++){
        int row = mt*16 + quad*4 + reg;
        int g = gids[row];
        if(g >= 0){
          Kn[(size_t)g*DD + colg] = f2bf(accK[mt][nt][reg] + bkv);
          Qn[(size_t)g*DD + colg] = accQ[mt][nt][reg] + bqv;
          Vn[(size_t)g*DD + colg] = f2bf(accV[mt][nt][reg] + bvv);
        }
      }
    }
  }
}

// ---------------- QA[n,r,h,k] = (prior/sqrtK) * sum_l A[r,h,k,l]*Qn[n,h,l] ----------------
__global__ __launch_bounds__(256) void k_qa(
    const float* __restrict__ Qn, const float* __restrict__ rel_att,
    const float* __restrict__ rel_prior, u16* __restrict__ QA)
{
  __shared__ float At[NH*KK*33];    // [h][l][k], padded to kill bank conflicts
  __shared__ float qs[16*DD];
  int tid = threadIdx.x;
  int r = blockIdx.y;
  int n0 = blockIdx.x * 16;
  const float* A = rel_att + r*NH*KK*KK;
  #pragma unroll
  for(int it=0; it<32; it++){
    int idx = tid + it*256;
    int h = idx >> 10, k = (idx >> 5) & 31, l = idx & 31;
    At[(h*KK + l)*33 + k] = A[idx];
  }
  #pragma unroll
  for(int it=0; it<4; it++){
    int f4 = tid + it*256;
    ((float4*)qs)[f4] = ((const float4*)(Qn + (size_t)n0*DD))[f4];
  }
  __syncthreads();
  int h = tid >> 5, k = tid & 31;
  float areg[KK];
  #pragma unroll
  for(int l=0;l<KK;l++) areg[l] = At[(h*KK + l)*33 + k];
  float scale = rel_prior[r*NH + h] * 0.17677669529663687f;  // 1/sqrt(32)
  for(int n=0;n<16;n++){
    float s = 0.f;
    #pragma unroll
    for(int l4=0;l4<8;l4++){
      float4 q = ((const float4*)(qs + n*DD + h*KK))[l4];
      s += areg[l4*4+0]*q.x + areg[l4*4+1]*q.y + areg[l4*4+2]*q.z + areg[l4*4+3]*q.w;
    }
    QA[((size_t)(n0+n)*NR + r)*DD + tid] = f2bf(s*scale);
  }
}

// ---------------- fused per-node softmax + aggregation (wave per node, no atomics) --------
__global__ __launch_bounds__(256) void k_edge(
    const u16* __restrict__ Kn, const u16* __restrict__ Vn, const u16* __restrict__ QA,
    const int* __restrict__ row_off, const int* __restrict__ packed,
    u16* __restrict__ aggrV)
{
  int lane = threadIdx.x & 63;
  int n = blockIdx.x*4 + (threadIdx.x >> 6);
  if(n >= NN) return;
  int off = lane*4;                  // = h*32 + j*4 with h=lane>>3
  float4 qa0,qa1,qa2,qa3,qa4;
  {
    const u16* qp = QA + (size_t)n*NR*DD + off;
    ushort4 q;
    q = *(const ushort4*)(qp + 0*DD); qa0 = make_float4(bf2f(q.x),bf2f(q.y),bf2f(q.z),bf2f(q.w));
    q = *(const ushort4*)(qp + 1*DD); qa1 = make_float4(bf2f(q.x),bf2f(q.y),bf2f(q.z),bf2f(q.w));
    q = *(const ushort4*)(qp + 2*DD); qa2 = make_float4(bf2f(q.x),bf2f(q.y),bf2f(q.z),bf2f(q.w));
    q = *(const ushort4*)(qp + 3*DD); qa3 = make_float4(bf2f(q.x),bf2f(q.y),bf2f(q.z),bf2f(q.w));
    q = *(const ushort4*)(qp + 4*DD); qa4 = make_float4(bf2f(q.x),bf2f(q.y),bf2f(q.z),bf2f(q.w));
  }
  float4 a0=make_float4(0,0,0,0), a1=a0, a2=a0, a3=a0, a4=a0;
  float s = 0.f;
  int e0 = row_off[n], e1 = row_off[n+1];
  for(int e=e0; e<e1; e++){
    int pk = packed[e];              // wave-uniform
    int src = pk & 0xFFFFF;
    int r = pk >> 20;
    ushort4 ku = *(const ushort4*)(Kn + (size_t)src*DD + off);
    ushort4 vu = *(const ushort4*)(Vn + (size_t)src*DD + off);
    float4 kv = make_float4(bf2f(ku.x),bf2f(ku.y),bf2f(ku.z),bf2f(ku.w));
    float4 vv = make_float4(bf2f(vu.x),bf2f(vu.y),bf2f(vu.z),bf2f(vu.w));
    float4 q;
    switch(r){ case 0: q=qa0; break; case 1: q=qa1; break; case 2: q=qa2; break;
               case 3: q=qa3; break; default: q=qa4; }
    float d = kv.x*q.x + kv.y*q.y + kv.z*q.z + kv.w*q.w;
    d += __shfl_xor(d, 1);           // butterfly within the 8-lane head group
    d += __shfl_xor(d, 2);
    d += __shfl_xor(d, 4);
    float p = __expf(d);             // no max-subtract: logits ~O(1), fp32-safe
    s += p;
    switch(r){
      case 0: a0.x+=p*vv.x; a0.y+=p*vv.y; a0.z+=p*vv.z; a0.w+=p*vv.w; break;
      case 1: a1.x+=p*vv.x; a1.y+=p*vv.y; a1.z+=p*vv.z; a1.w+=p*vv.w; break;
      case 2: a2.x+=p*vv.x; a2.y+=p*vv.y; a2.z+=p*vv.z; a2.w+=p*vv.w; break;
      case 3: a3.x+=p*vv.x; a3.y+=p*vv.y; a3.z+=p*vv.z; a3.w+=p*vv.w; break;
      default:a4.x+=p*vv.x; a4.y+=p*vv.y; a4.z+=p*vv.z; a4.w+=p*vv.w; break;
    }
  }
  float inv = (s > 0.f) ? (1.f/s) : 0.f;
  u16* op = aggrV + (size_t)n*NR*DD + off;
  #define ST(ptr, a) { ushort4 o; o.x=f2bf((a).x*inv); o.y=f2bf((a).y*inv); \
                       o.z=f2bf((a).z*inv); o.w=f2bf((a).w*inv); *(ushort4*)(ptr)=o; }
  ST(op + 0*DD, a0); ST(op + 1*DD, a1); ST(op + 2*DD, a2); ST(op + 3*DD, a3); ST(op + 4*DD, a4);
  #undef ST
}

// ---------------- apply rel_msg per (node, r), sum over r, ELU ----------------
__global__ __launch_bounds__(256) void k_msg(
    const u16* __restrict__ aggrV, const float* __restrict__ rel_msg,
    float* __restrict__ h1)
{
  __shared__ float Ms[NH*KK*KK];     // [h][k][l]
  __shared__ ushort4 Vs[32*64];      // 32 nodes x 256 bf16
  int tid = threadIdx.x;
  int n0 = blockIdx.x*32;
  int h = tid >> 5, l = tid & 31;
  float acc[32];
  #pragma unroll
  for(int n=0;n<32;n++) acc[n]=0.f;
  for(int r=0;r<NR;r++){
    #pragma unroll
    for(int it=0; it<32; it++){
      int idx = tid + it*256;
      Ms[idx] = rel_msg[r*8192 + idx];
    }
    #pragma unroll
    for(int it=0; it<8; it++){
      int f4 = tid + it*256;
      int row = f4 >> 6, c4 = f4 & 63;
      Vs[f4] = ((const ushort4*)(aggrV + ((size_t)(n0+row)*NR + r)*DD))[c4];
    }
    __syncthreads();
    float mreg[KK];
    #pragma unroll
    for(int k=0;k<KK;k++) mreg[k] = Ms[h*1024 + k*KK + l];
    for(int n=0;n<32;n++){
      #pragma unroll
      for(int k4=0;k4<8;k4++){
        ushort4 v = Vs[n*64 + h*8 + k4];
        acc[n] += mreg[k4*4+0]*bf2f(v.x) + mreg[k4*4+1]*bf2f(v.y)
                + mreg[k4*4+2]*bf2f(v.z) + mreg[k4*4+3]*bf2f(v.w);
      }
    }
    __syncthreads();
  }
  for(int n=0;n<32;n++){
    float v = acc[n];
    v = (v > 0.f) ? v : expm1f(v);
    h1[(size_t)(n0+n)*DD + tid] = v;
  }
}

// ---------------- typed Wa + residual + classifier + log_softmax ----------------
__global__ __launch_bounds__(256) void k_out(
    const float* __restrict__ h1, const float* __restrict__ x,
    const int* __restrict__ perm, const int* __restrict__ boff,
    const float* __restrict__ Wa, const float* __restrict__ ba,
    const float* __restrict__ Wo, const float* __restrict__ bo,
    float* __restrict__ out)
{
  __shared__ float hs[32*DD];
  __shared__ float wo[DD*NC];
  __shared__ float cls[32*NC];
  __shared__ int gids[32];
  int tid = threadIdx.x;
  int ts = blockIdx.x*32;
  int t = (ts >= boff[2]) ? 2 : (ts >= boff[1]) ? 1 : 0;
  if(tid < 32) gids[tid] = perm[ts + tid];
  #pragma unroll
  for(int it=0; it<16; it++) wo[tid + it*256] = Wo[tid + it*256];
  __syncthreads();
  #pragma unroll
  for(int it=0; it<8; it++){
    int f4 = tid + it*256;
    int row = f4 >> 6, c4 = f4 & 63;
    int g = gids[row];
    float4 v = make_float4(0.f,0.f,0.f,0.f);
    if(g >= 0) v = ((const float4*)(h1 + (size_t)g*DD))[c4];
    ((float4*)hs)[f4] = v;
  }
  __syncthreads();
  float acc[32];
  #pragma unroll
  for(int n=0;n<32;n++) acc[n]=0.f;
  const float* wa = Wa + t*65536 + tid;
  for(int i=0;i<DD;i+=4){
    float w0=wa[(i+0)*DD], w1=wa[(i+1)*DD], w2=wa[(i+2)*DD], w3=wa[(i+3)*DD];
    #pragma unroll
    for(int n=0;n<32;n++){
      float4 xv = ((const float4*)(hs + n*DD))[i>>2];
      acc[n] += xv.x*w0 + xv.y*w1 + xv.z*w2 + xv.w*w3;
    }
  }
  float bav = ba[t*DD + tid];
  float h2v[32];
  for(int n=0;n<32;n++){
    int g = gids[n];
    float xr = (g>=0) ? x[(size_t)g*DD + tid] : 0.f;
    h2v[n] = acc[n] + bav + xr;
  }
  __syncthreads();
  for(int n=0;n<32;n++) hs[n*DD + tid] = h2v[n];
  __syncthreads();
  {
    int n = tid >> 3, q = tid & 7;
    int c0 = q*2;
    float s0 = bo[c0], s1 = bo[c0+1];
    for(int i=0;i<DD;i++){
      float hv = hs[n*DD + i];
      s0 += hv * wo[i*NC + c0];
      s1 += hv * wo[i*NC + c0 + 1];
    }
    cls[n*NC + c0] = s0;
    cls[n*NC + c0 + 1] = s1;
  }
  __syncthreads();
  if(tid < 32){
    int g = gids[tid];
    if(g >= 0){
      float m = -1e30f;
      #pragma unroll
      for(int c=0;c<NC;c++) m = fmaxf(m, cls[tid*NC + c]);
      float sum = 0.f;
      #pragma unroll
      for(int c=0;c<NC;c++) sum += __expf(cls[tid*NC + c] - m);
      float lse = m + __logf(sum);
      #pragma unroll
      for(int c=0;c<NC;c++) out[(size_t)g*NC + c] = cls[tid*NC + c] - lse;
    }
  }
}

extern "C" void kernel_launch(void* const* d_in, const int* in_sizes, int n_in,
                              void* d_out, int out_size, void* d_ws, size_t ws_size,
                              hipStream_t stream)
{
  const float* x     = (const float*)d_in[0];
  const int*   ei    = (const int*)d_in[1];
  const int*   ntype = (const int*)d_in[2];
  const int*   etype = (const int*)d_in[3];
  const float* Wk    = (const float*)d_in[4];
  const float* bk    = (const float*)d_in[5];
  const float* Wq    = (const float*)d_in[6];
  const float* bq    = (const float*)d_in[7];
  const float* Wv    = (const float*)d_in[8];
  const float* bv    = (const float*)d_in[9];
  const float* Wa    = (const float*)d_in[10];
  const float* ba    = (const float*)d_in[11];
  const float* prior = (const float*)d_in[12];
  const float* ratt  = (const float*)d_in[13];
  const float* rmsg  = (const float*)d_in[14];
  const float* Wo    = (const float*)d_in[15];
  const float* bo    = (const float*)d_in[16];
  float* out = (float*)d_out;

  char* ws = (char*)d_ws;
  int* iw      = (int*)ws;
  int* cnt     = iw + 0;
  int* bcur    = iw + 4;
  int* boff    = iw + 8;
  int* deg     = iw + 16;
  int* cursor  = iw + 16 + NN;
  int* row_off = iw + 16 + 2*NN;          // NN+1 entries
  int* perm    = iw + 60032;              // 628*32 = 20096 entries
  int* packed  = iw + 80128;              // NE entries; ends at int 400128

  size_t fb = 1600512;                    // bytes (400128 ints), 256-aligned
  float* Qn    = (float*)(ws + fb); fb += 4ull*NN*DD;
  float* h1    = (float*)(ws + fb); fb += 4ull*NN*DD;
  u16*   Kn    = (u16*)(ws + fb);   fb += 2ull*NN*DD;
  u16*   Vn    = (u16*)(ws + fb);   fb += 2ull*NN*DD;
  u16*   QA    = (u16*)(ws + fb);   fb += 2ull*NN*NR*DD;
  u16*   aggrV = (u16*)(ws + fb);   fb += 2ull*NN*NR*DD;
  // aliases: xb lives in aggrV's region (dead until k_edge),
  // transposed bf16 weights live in h1's region (dead until k_msg).
  u16* xb  = aggrV;                       // NN*DD bf16 = 10.24 MB <= 51.2 MB
  u16* Wtk = (u16*)h1;                    // 3*65536 bf16 each
  u16* Wtq = Wtk + 3*65536;
  u16* Wtv = Wtq + 3*65536;               // total 1.18 MB <= 20.48 MB

  hipMemsetAsync(iw, 0, (size_t)(16 + 2*NN)*sizeof(int), stream);      // cnt,bcur,boff,deg,cursor
  hipMemsetAsync(perm, 0xFF, (size_t)20096*sizeof(int), stream);       // perm = -1

  k_nb_count  <<<79, 256, 0, stream>>>(ntype, cnt);
  k_nb_off    <<<1, 1, 0, stream>>>(cnt, boff);
  k_nb_scatter<<<79, 256, 0, stream>>>(ntype, boff, bcur, perm);
  k_deg       <<<1250, 256, 0, stream>>>(ei, deg);
  k_scan      <<<1, 1024, 0, stream>>>(deg, row_off);
  k_escatter  <<<1250, 256, 0, stream>>>(ei, etype, row_off, cursor, packed);
  k_castx     <<<2500, 256, 0, stream>>>(x, xb);
  k_castw     <<<dim3(8,8,9), 256, 0, stream>>>(Wk, Wq, Wv, Wtk, Wtq, Wtv);
  k_proj      <<<628, 256, 0, stream>>>(xb, perm, boff, Wtk, Wtq, Wtv, bk, bq, bv, Kn, Qn, Vn);
  k_qa        <<<dim3(1250,5), 256, 0, stream>>>(Qn, ratt, prior, QA);
  k_edge      <<<5000, 256, 0, stream>>>(Kn, Vn, QA, row_off, packed, aggrV);
  k_msg       <<<625, 256, 0, stream>>>(aggrV, rmsg, h1);
  k_out       <<<628, 256, 0, stream>>>(h1, x, perm, boff, Wa, ba, Wo, bo, out);
}

// Round 3
// 695.617 us; speedup vs baseline: 1.3296x; 1.2057x over previous
//
#include <hip/hip_runtime.h>
#include <hip/hip_bf16.h>
#include <math.h>

#define NN 20000
#define NE 320000
#define DD 256
#define NH 8
#define KK 32
#define NR 5
#define NC 16

typedef unsigned short u16;
typedef unsigned int u32;
typedef __attribute__((ext_vector_type(8))) short bf16x8;
typedef __attribute__((ext_vector_type(4))) float f32x4;

__device__ __forceinline__ float bf2f(u16 v){ return __uint_as_float(((u32)v)<<16); }
__device__ __forceinline__ u16 f2bf(float f){
  u32 u = __float_as_uint(f);
  return (u16)((u + 0x7FFFu + ((u>>16)&1u)) >> 16);
}

// ---------------- node bucketing by type (for typed GEMMs) ----------------
__global__ void k_nb_count(const int* __restrict__ ntype, int* __restrict__ cnt){
  int n = blockIdx.x*256 + threadIdx.x;
  if(n < NN) atomicAdd(&cnt[ntype[n]], 1);
}
__global__ void k_nb_off(const int* __restrict__ cnt, int* __restrict__ boff){
  int a = (cnt[0]+31)&~31;
  int b = (cnt[1]+31)&~31;
  boff[0]=0; boff[1]=a; boff[2]=a+b;
}
// wave-aggregated: ONE atomic per wave per type (was: one per node -> 162us
// of same-address atomic serialization at ~8ns each). Order within a type
// bucket is arbitrary by construction, so ballot-rank placement is valid.
__global__ void k_nb_scatter(const int* __restrict__ ntype, const int* __restrict__ boff,
                             int* __restrict__ bcur, int* __restrict__ perm){
  int n = blockIdx.x*256 + threadIdx.x;
  int t = (n < NN) ? ntype[n] : -1;
  int lane = threadIdx.x & 63;
  #pragma unroll
  for(int tt=0; tt<3; tt++){
    unsigned long long mask = __ballot(t == tt);
    if(t == tt){
      int rank = __popcll(mask & ((1ull<<lane)-1ull));
      int leader = __ffsll((long long)mask) - 1;
      int base = 0;
      if(lane == leader) base = atomicAdd(&bcur[tt], __popcll(mask));
      base = __shfl(base, leader);
      perm[boff[tt] + base + rank] = n;
    }
  }
}

// ---------------- CSR by dst ----------------
__global__ void k_deg(const int* __restrict__ ei, int* __restrict__ deg){
  int e = blockIdx.x*256 + threadIdx.x;
  if(e < NE) atomicAdd(&deg[ei[NE + e]], 1);
}
__global__ void k_scan(const int* __restrict__ deg, int* __restrict__ row_off){
  __shared__ int sums[1024];
  int t = threadIdx.x;
  const int CH = 20;                 // 1024*20 >= NN
  int local[CH];
  int s = 0;
  #pragma unroll
  for(int j=0;j<CH;j++){
    int i = t*CH + j;
    local[j] = s;
    s += (i < NN) ? deg[i] : 0;
  }
  sums[t] = s;
  __syncthreads();
  for(int off=1; off<1024; off<<=1){
    int v = (t>=off) ? sums[t-off] : 0;
    __syncthreads();
    if(t>=off) sums[t] += v;
    __syncthreads();
  }
  int base = (t==0) ? 0 : sums[t-1];
  #pragma unroll
  for(int j=0;j<CH;j++){
    int i = t*CH + j;
    if(i < NN) row_off[i] = base + local[j];
  }
  if(t==1023) row_off[NN] = sums[1023];
}
__global__ void k_escatter(const int* __restrict__ ei, const int* __restrict__ etype,
                           const int* __restrict__ row_off, int* __restrict__ cursor,
                           int* __restrict__ packed){
  int e = blockIdx.x*256 + threadIdx.x;
  if(e < NE){
    int dst = ei[NE+e];
    int pos = row_off[dst] + atomicAdd(&cursor[dst],1);
    packed[pos] = ei[e] | (etype[e] << 20);   // src < 2^20, r in bits 20..22
  }
}

// ---------------- prep: cast x -> bf16 ----------------
__global__ void k_castx(const float* __restrict__ x, u16* __restrict__ xb){
  int i = blockIdx.x*256 + threadIdx.x;     // 8 floats per thread; 2500 blocks
  float4 v0 = ((const float4*)x)[i*2+0];
  float4 v1 = ((const float4*)x)[i*2+1];
  uint4 o;
  o.x = (u32)f2bf(v0.x) | ((u32)f2bf(v0.y)<<16);
  o.y = (u32)f2bf(v0.z) | ((u32)f2bf(v0.w)<<16);
  o.z = (u32)f2bf(v1.x) | ((u32)f2bf(v1.y)<<16);
  o.w = (u32)f2bf(v1.z) | ((u32)f2bf(v1.w)<<16);
  ((uint4*)xb)[i] = o;
}

// ---------------- prep: transpose + cast Wk/Wq/Wv -> bf16 [t][out][in] ----------------
__global__ __launch_bounds__(256) void k_castw(
  const float* __restrict__ Wk, const float* __restrict__ Wq, const float* __restrict__ Wv,
  u16* __restrict__ Wtk, u16* __restrict__ Wtq, u16* __restrict__ Wtv)
{
  __shared__ float tile[32][33];
  int z = blockIdx.z;                       // 0..8: tensor*3 + t
  int tensor = z/3, t = z%3;
  const float* W = (tensor==0) ? Wk : (tensor==1) ? Wq : Wv;
  u16* O = (tensor==0) ? Wtk : (tensor==1) ? Wtq : Wtv;
  int i0 = blockIdx.x*32, j0 = blockIdx.y*32;
  int rr = threadIdx.x>>5, cc = threadIdx.x&31;
  #pragma unroll
  for(int p=0;p<4;p++)
    tile[rr+p*8][cc] = W[t*65536 + (i0+rr+p*8)*256 + j0+cc];
  __syncthreads();
  #pragma unroll
  for(int p=0;p<4;p++)
    O[t*65536 + (j0+rr+p*8)*256 + i0+cc] = f2bf(tile[cc][rr+p*8]);
}

// ---------------- typed K/Q/V projections via MFMA 16x16x32 bf16 ----------------
__global__ __launch_bounds__(256) void k_proj(
    const u16* __restrict__ xb, const int* __restrict__ perm, const int* __restrict__ boff,
    const u16* __restrict__ Wtk, const u16* __restrict__ Wtq, const u16* __restrict__ Wtv,
    const float* __restrict__ bk, const float* __restrict__ bq, const float* __restrict__ bv,
    u16* __restrict__ Kn, float* __restrict__ Qn, u16* __restrict__ Vn)
{
  __shared__ u16 xs[32*DD];
  __shared__ int gids[32];
  int tid = threadIdx.x;
  int ts = blockIdx.x*32;
  int t = (ts >= boff[2]) ? 2 : (ts >= boff[1]) ? 1 : 0;   // boff 32-aligned
  if(tid < 32) gids[tid] = perm[ts + tid];
  __syncthreads();
  #pragma unroll
  for(int it=0; it<4; it++){
    int q = tid + it*256;
    int row = q >> 5, c = q & 31;
    int g = gids[row];
    uint4 v = make_uint4(0,0,0,0);
    if(g >= 0) v = ((const uint4*)(xb + (size_t)g*DD))[c];
    ((uint4*)xs)[q] = v;
  }
  __syncthreads();
  int lane = tid & 63;
  int w = tid >> 6;
  int quad = lane >> 4;
  int l16 = lane & 15;
  f32x4 accK[2][4], accQ[2][4], accV[2][4];
  #pragma unroll
  for(int mt=0;mt<2;mt++)
    #pragma unroll
    for(int nt=0;nt<4;nt++){
      accK[mt][nt]=(f32x4)(0.f); accQ[mt][nt]=(f32x4)(0.f); accV[mt][nt]=(f32x4)(0.f);
    }
  const u16* wkp = Wtk + (size_t)t*65536;
  const u16* wqp = Wtq + (size_t)t*65536;
  const u16* wvp = Wtv + (size_t)t*65536;
  #pragma unroll
  for(int kk=0; kk<8; kk++){
    int kb = kk*32 + quad*8;
    bf16x8 a0 = *(const bf16x8*)(xs + l16*DD + kb);
    bf16x8 a1 = *(const bf16x8*)(xs + (16+l16)*DD + kb);
    #pragma unroll
    for(int nt=0; nt<4; nt++){
      int n = w*64 + nt*16 + l16;
      bf16x8 bK = *(const bf16x8*)(wkp + (size_t)n*DD + kb);
      bf16x8 bQ = *(const bf16x8*)(wqp + (size_t)n*DD + kb);
      bf16x8 bV = *(const bf16x8*)(wvp + (size_t)n*DD + kb);
      accK[0][nt] = __builtin_amdgcn_mfma_f32_16x16x32_bf16(a0, bK, accK[0][nt], 0,0,0);
      accK[1][nt] = __builtin_amdgcn_mfma_f32_16x16x32_bf16(a1, bK, accK[1][nt], 0,0,0);
      accQ[0][nt] = __builtin_amdgcn_mfma_f32_16x16x32_bf16(a0, bQ, accQ[0][nt], 0,0,0);
      accQ[1][nt] = __builtin_amdgcn_mfma_f32_16x16x32_bf16(a1, bQ, accQ[1][nt], 0,0,0);
      accV[0][nt] = __builtin_amdgcn_mfma_f32_16x16x32_bf16(a0, bV, accV[0][nt], 0,0,0);
      accV[1][nt] = __builtin_amdgcn_mfma_f32_16x16x32_bf16(a1, bV, accV[1][nt], 0,0,0);
    }
  }
  #pragma unroll
  for(int nt=0; nt<4; nt++){
    int colg = w*64 + nt*16 + l16;
    float bkv = bk[t*DD+colg], bqv = bq[t*DD+colg], bvv = bv[t*DD+colg];
    #pragma unroll
    for(int mt=0; mt<2; mt++){
      #pragma unroll
      for(int reg=0; reg<4; reg++){
        int row = mt*16 + quad*4 + reg;
        int g = gids[row];
        if(g >= 0){
          Kn[(size_t)g*DD + colg] = f2bf(accK[mt][nt][reg] + bkv);
          Qn[(size_t)g*DD + colg] = accQ[mt][nt][reg] + bqv;
          Vn[(size_t)g*DD + colg] = f2bf(accV[mt][nt][reg] + bvv);
        }
      }
    }
  }
}

// ---------------- QA[n,r,h,k] = (prior/sqrtK) * sum_l A[r,h,k,l]*Qn[n,h,l] ----------------
__global__ __launch_bounds__(256) void k_qa(
    const float* __restrict__ Qn, const float* __restrict__ rel_att,
    const float* __restrict__ rel_prior, u16* __restrict__ QA)
{
  __shared__ float At[NH*KK*33];    // [h][l][k], padded to kill bank conflicts
  __shared__ float qs[16*DD];
  int tid = threadIdx.x;
  int r = blockIdx.y;
  int n0 = blockIdx.x * 16;
  const float* A = rel_att + r*NH*KK*KK;
  #pragma unroll
  for(int it=0; it<32; it++){
    int idx = tid + it*256;
    int h = idx >> 10, k = (idx >> 5) & 31, l = idx & 31;
    At[(h*KK + l)*33 + k] = A[idx];
  }
  #pragma unroll
  for(int it=0; it<4; it++){
    int f4 = tid + it*256;
    ((float4*)qs)[f4] = ((const float4*)(Qn + (size_t)n0*DD))[f4];
  }
  __syncthreads();
  int h = tid >> 5, k = tid & 31;
  float areg[KK];
  #pragma unroll
  for(int l=0;l<KK;l++) areg[l] = At[(h*KK + l)*33 + k];
  float scale = rel_prior[r*NH + h] * 0.17677669529663687f;  // 1/sqrt(32)
  for(int n=0;n<16;n++){
    float s = 0.f;
    #pragma unroll
    for(int l4=0;l4<8;l4++){
      float4 q = ((const float4*)(qs + n*DD + h*KK))[l4];
      s += areg[l4*4+0]*q.x + areg[l4*4+1]*q.y + areg[l4*4+2]*q.z + areg[l4*4+3]*q.w;
    }
    QA[((size_t)(n0+n)*NR + r)*DD + tid] = f2bf(s*scale);
  }
}

// ---------------- fused per-node softmax + aggregation (wave per node, no atomics) --------
__global__ __launch_bounds__(256) void k_edge(
    const u16* __restrict__ Kn, const u16* __restrict__ Vn, const u16* __restrict__ QA,
    const int* __restrict__ row_off, const int* __restrict__ packed,
    u16* __restrict__ aggrV)
{
  int lane = threadIdx.x & 63;
  int n = blockIdx.x*4 + (threadIdx.x >> 6);
  if(n >= NN) return;
  int off = lane*4;                  // = h*32 + j*4 with h=lane>>3
  float4 qa0,qa1,qa2,qa3,qa4;
  {
    const u16* qp = QA + (size_t)n*NR*DD + off;
    ushort4 q;
    q = *(const ushort4*)(qp + 0*DD); qa0 = make_float4(bf2f(q.x),bf2f(q.y),bf2f(q.z),bf2f(q.w));
    q = *(const ushort4*)(qp + 1*DD); qa1 = make_float4(bf2f(q.x),bf2f(q.y),bf2f(q.z),bf2f(q.w));
    q = *(const ushort4*)(qp + 2*DD); qa2 = make_float4(bf2f(q.x),bf2f(q.y),bf2f(q.z),bf2f(q.w));
    q = *(const ushort4*)(qp + 3*DD); qa3 = make_float4(bf2f(q.x),bf2f(q.y),bf2f(q.z),bf2f(q.w));
    q = *(const ushort4*)(qp + 4*DD); qa4 = make_float4(bf2f(q.x),bf2f(q.y),bf2f(q.z),bf2f(q.w));
  }
  float4 a0=make_float4(0,0,0,0), a1=a0, a2=a0, a3=a0, a4=a0;
  float s = 0.f;
  int e0 = row_off[n], e1 = row_off[n+1];
  for(int e=e0; e<e1; e++){
    int pk = packed[e];              // wave-uniform
    int src = pk & 0xFFFFF;
    int r = pk >> 20;
    ushort4 ku = *(const ushort4*)(Kn + (size_t)src*DD + off);
    ushort4 vu = *(const ushort4*)(Vn + (size_t)src*DD + off);
    float4 kv = make_float4(bf2f(ku.x),bf2f(ku.y),bf2f(ku.z),bf2f(ku.w));
    float4 vv = make_float4(bf2f(vu.x),bf2f(vu.y),bf2f(vu.z),bf2f(vu.w));
    float4 q;
    switch(r){ case 0: q=qa0; break; case 1: q=qa1; break; case 2: q=qa2; break;
               case 3: q=qa3; break; default: q=qa4; }
    float d = kv.x*q.x + kv.y*q.y + kv.z*q.z + kv.w*q.w;
    d += __shfl_xor(d, 1);           // butterfly within the 8-lane head group
    d += __shfl_xor(d, 2);
    d += __shfl_xor(d, 4);
    float p = __expf(d);             // no max-subtract: logits ~O(1), fp32-safe
    s += p;
    switch(r){
      case 0: a0.x+=p*vv.x; a0.y+=p*vv.y; a0.z+=p*vv.z; a0.w+=p*vv.w; break;
      case 1: a1.x+=p*vv.x; a1.y+=p*vv.y; a1.z+=p*vv.z; a1.w+=p*vv.w; break;
      case 2: a2.x+=p*vv.x; a2.y+=p*vv.y; a2.z+=p*vv.z; a2.w+=p*vv.w; break;
      case 3: a3.x+=p*vv.x; a3.y+=p*vv.y; a3.z+=p*vv.z; a3.w+=p*vv.w; break;
      default:a4.x+=p*vv.x; a4.y+=p*vv.y; a4.z+=p*vv.z; a4.w+=p*vv.w; break;
    }
  }
  float inv = (s > 0.f) ? (1.f/s) : 0.f;
  u16* op = aggrV + (size_t)n*NR*DD + off;
  #define ST(ptr, a) { ushort4 o; o.x=f2bf((a).x*inv); o.y=f2bf((a).y*inv); \
                       o.z=f2bf((a).z*inv); o.w=f2bf((a).w*inv); *(ushort4*)(ptr)=o; }
  ST(op + 0*DD, a0); ST(op + 1*DD, a1); ST(op + 2*DD, a2); ST(op + 3*DD, a3); ST(op + 4*DD, a4);
  #undef ST
}

// ---------------- apply rel_msg per (node, r), sum over r, ELU ----------------
__global__ __launch_bounds__(256) void k_msg(
    const u16* __restrict__ aggrV, const float* __restrict__ rel_msg,
    float* __restrict__ h1)
{
  __shared__ float Ms[NH*KK*KK];     // [h][k][l]
  __shared__ ushort4 Vs[32*64];      // 32 nodes x 256 bf16
  int tid = threadIdx.x;
  int n0 = blockIdx.x*32;
  int h = tid >> 5, l = tid & 31;
  float acc[32];
  #pragma unroll
  for(int n=0;n<32;n++) acc[n]=0.f;
  for(int r=0;r<NR;r++){
    #pragma unroll
    for(int it=0; it<32; it++){
      int idx = tid + it*256;
      Ms[idx] = rel_msg[r*8192 + idx];
    }
    #pragma unroll
    for(int it=0; it<8; it++){
      int f4 = tid + it*256;
      int row = f4 >> 6, c4 = f4 & 63;
      Vs[f4] = ((const ushort4*)(aggrV + ((size_t)(n0+row)*NR + r)*DD))[c4];
    }
    __syncthreads();
    float mreg[KK];
    #pragma unroll
    for(int k=0;k<KK;k++) mreg[k] = Ms[h*1024 + k*KK + l];
    for(int n=0;n<32;n++){
      #pragma unroll
      for(int k4=0;k4<8;k4++){
        ushort4 v = Vs[n*64 + h*8 + k4];
        acc[n] += mreg[k4*4+0]*bf2f(v.x) + mreg[k4*4+1]*bf2f(v.y)
                + mreg[k4*4+2]*bf2f(v.z) + mreg[k4*4+3]*bf2f(v.w);
      }
    }
    __syncthreads();
  }
  for(int n=0;n<32;n++){
    float v = acc[n];
    v = (v > 0.f) ? v : expm1f(v);
    h1[(size_t)(n0+n)*DD + tid] = v;
  }
}

// ---------------- typed Wa + residual + classifier + log_softmax ----------------
__global__ __launch_bounds__(256) void k_out(
    const float* __restrict__ h1, const float* __restrict__ x,
    const int* __restrict__ perm, const int* __restrict__ boff,
    const float* __restrict__ Wa, const float* __restrict__ ba,
    const float* __restrict__ Wo, const float* __restrict__ bo,
    float* __restrict__ out)
{
  __shared__ float hs[32*DD];
  __shared__ float wo[DD*NC];
  __shared__ float cls[32*NC];
  __shared__ int gids[32];
  int tid = threadIdx.x;
  int ts = blockIdx.x*32;
  int t = (ts >= boff[2]) ? 2 : (ts >= boff[1]) ? 1 : 0;
  if(tid < 32) gids[tid] = perm[ts + tid];
  #pragma unroll
  for(int it=0; it<16; it++) wo[tid + it*256] = Wo[tid + it*256];
  __syncthreads();
  #pragma unroll
  for(int it=0; it<8; it++){
    int f4 = tid + it*256;
    int row = f4 >> 6, c4 = f4 & 63;
    int g = gids[row];
    float4 v = make_float4(0.f,0.f,0.f,0.f);
    if(g >= 0) v = ((const float4*)(h1 + (size_t)g*DD))[c4];
    ((float4*)hs)[f4] = v;
  }
  __syncthreads();
  float acc[32];
  #pragma unroll
  for(int n=0;n<32;n++) acc[n]=0.f;
  const float* wa = Wa + t*65536 + tid;
  for(int i=0;i<DD;i+=4){
    float w0=wa[(i+0)*DD], w1=wa[(i+1)*DD], w2=wa[(i+2)*DD], w3=wa[(i+3)*DD];
    #pragma unroll
    for(int n=0;n<32;n++){
      float4 xv = ((const float4*)(hs + n*DD))[i>>2];
      acc[n] += xv.x*w0 + xv.y*w1 + xv.z*w2 + xv.w*w3;
    }
  }
  float bav = ba[t*DD + tid];
  float h2v[32];
  for(int n=0;n<32;n++){
    int g = gids[n];
    float xr = (g>=0) ? x[(size_t)g*DD + tid] : 0.f;
    h2v[n] = acc[n] + bav + xr;
  }
  __syncthreads();
  for(int n=0;n<32;n++) hs[n*DD + tid] = h2v[n];
  __syncthreads();
  {
    int n = tid >> 3, q = tid & 7;
    int c0 = q*2;
    float s0 = bo[c0], s1 = bo[c0+1];
    for(int i=0;i<DD;i++){
      float hv = hs[n*DD + i];
      s0 += hv * wo[i*NC + c0];
      s1 += hv * wo[i*NC + c0 + 1];
    }
    cls[n*NC + c0] = s0;
    cls[n*NC + c0 + 1] = s1;
  }
  __syncthreads();
  if(tid < 32){
    int g = gids[tid];
    if(g >= 0){
      float m = -1e30f;
      #pragma unroll
      for(int c=0;c<NC;c++) m = fmaxf(m, cls[tid*NC + c]);
      float sum = 0.f;
      #pragma unroll
      for(int c=0;c<NC;c++) sum += __expf(cls[tid*NC + c] - m);
      float lse = m + __logf(sum);
      #pragma unroll
      for(int c=0;c<NC;c++) out[(size_t)g*NC + c] = cls[tid*NC + c] - lse;
    }
  }
}

extern "C" void kernel_launch(void* const* d_in, const int* in_sizes, int n_in,
                              void* d_out, int out_size, void* d_ws, size_t ws_size,
                              hipStream_t stream)
{
  const float* x     = (const float*)d_in[0];
  const int*   ei    = (const int*)d_in[1];
  const int*   ntype = (const int*)d_in[2];
  const int*   etype = (const int*)d_in[3];
  const float* Wk    = (const float*)d_in[4];
  const float* bk    = (const float*)d_in[5];
  const float* Wq    = (const float*)d_in[6];
  const float* bq    = (const float*)d_in[7];
  const float* Wv    = (const float*)d_in[8];
  const float* bv    = (const float*)d_in[9];
  const float* Wa    = (const float*)d_in[10];
  const float* ba    = (const float*)d_in[11];
  const float* prior = (const float*)d_in[12];
  const float* ratt  = (const float*)d_in[13];
  const float* rmsg  = (const float*)d_in[14];
  const float* Wo    = (const float*)d_in[15];
  const float* bo    = (const float*)d_in[16];
  float* out = (float*)d_out;

  char* ws = (char*)d_ws;
  int* iw      = (int*)ws;
  int* cnt     = iw + 0;
  int* bcur    = iw + 4;
  int* boff    = iw + 8;
  int* deg     = iw + 16;
  int* cursor  = iw + 16 + NN;
  int* row_off = iw + 16 + 2*NN;          // NN+1 entries
  int* perm    = iw + 60032;              // 628*32 = 20096 entries
  int* packed  = iw + 80128;              // NE entries; ends at int 400128

  size_t fb = 1600512;                    // bytes (400128 ints), 256-aligned
  float* Qn    = (float*)(ws + fb); fb += 4ull*NN*DD;
  float* h1    = (float*)(ws + fb); fb += 4ull*NN*DD;
  u16*   Kn    = (u16*)(ws + fb);   fb += 2ull*NN*DD;
  u16*   Vn    = (u16*)(ws + fb);   fb += 2ull*NN*DD;
  u16*   QA    = (u16*)(ws + fb);   fb += 2ull*NN*NR*DD;
  u16*   aggrV = (u16*)(ws + fb);   fb += 2ull*NN*NR*DD;
  // aliases: xb lives in aggrV's region (dead until k_edge),
  // transposed bf16 weights live in h1's region (dead until k_msg).
  u16* xb  = aggrV;                       // NN*DD bf16 = 10.24 MB <= 51.2 MB
  u16* Wtk = (u16*)h1;                    // 3*65536 bf16 each
  u16* Wtq = Wtk + 3*65536;
  u16* Wtv = Wtq + 3*65536;               // total 1.18 MB <= 20.48 MB

  hipMemsetAsync(iw, 0, (size_t)(16 + 2*NN)*sizeof(int), stream);      // cnt,bcur,boff,deg,cursor
  hipMemsetAsync(perm, 0xFF, (size_t)20096*sizeof(int), stream);       // perm = -1

  k_nb_count  <<<79, 256, 0, stream>>>(ntype, cnt);
  k_nb_off    <<<1, 1, 0, stream>>>(cnt, boff);
  k_nb_scatter<<<79, 256, 0, stream>>>(ntype, boff, bcur, perm);
  k_deg       <<<1250, 256, 0, stream>>>(ei, deg);
  k_scan      <<<1, 1024, 0, stream>>>(deg, row_off);
  k_escatter  <<<1250, 256, 0, stream>>>(ei, etype, row_off, cursor, packed);
  k_castx     <<<2500, 256, 0, stream>>>(x, xb);
  k_castw     <<<dim3(8,8,9), 256, 0, stream>>>(Wk, Wq, Wv, Wtk, Wtq, Wtv);
  k_proj      <<<628, 256, 0, stream>>>(xb, perm, boff, Wtk, Wtq, Wtv, bk, bq, bv, Kn, Qn, Vn);
  k_qa        <<<dim3(1250,5), 256, 0, stream>>>(Qn, ratt, prior, QA);
  k_edge      <<<5000, 256, 0, stream>>>(Kn, Vn, QA, row_off, packed, aggrV);
  k_msg       <<<625, 256, 0, stream>>>(aggrV, rmsg, h1);
  k_out       <<<628, 256, 0, stream>>>(h1, x, perm, boff, Wa, ba, Wo, bo, out);
}

// Round 4
// 581.072 us; speedup vs baseline: 1.5916x; 1.1971x over previous
//
#include <hip/hip_runtime.h>
#include <hip/hip_bf16.h>
#include <math.h>

#define NN 20000
#define NE 320000
#define DD 256
#define NH 8
#define KK 32
#define NR 5
#define NC 16

typedef unsigned short u16;
typedef unsigned int u32;
typedef __attribute__((ext_vector_type(8))) short bf16x8;
typedef __attribute__((ext_vector_type(4))) float f32x4;

__device__ __forceinline__ float bf2f(u16 v){ return __uint_as_float(((u32)v)<<16); }
__device__ __forceinline__ u16 f2bf(float f){
  u32 u = __float_as_uint(f);
  return (u16)((u + 0x7FFFu + ((u>>16)&1u)) >> 16);
}

// ---------------- node bucketing by type (for typed GEMMs) ----------------
// wave-aggregated: ONE atomic per wave per type (was: one per node -> 128us
// of same-address atomic serialization).
__global__ void k_nb_count(const int* __restrict__ ntype, int* __restrict__ cnt){
  int n = blockIdx.x*256 + threadIdx.x;
  int t = (n < NN) ? ntype[n] : -1;
  int lane = threadIdx.x & 63;
  #pragma unroll
  for(int tt=0; tt<3; tt++){
    unsigned long long mask = __ballot(t == tt);
    int leader = __ffsll((long long)mask) - 1;
    if(lane == leader) atomicAdd(&cnt[tt], __popcll(mask));
  }
}
__global__ void k_nb_off(const int* __restrict__ cnt, int* __restrict__ boff){
  int a = (cnt[0]+31)&~31;
  int b = (cnt[1]+31)&~31;
  boff[0]=0; boff[1]=a; boff[2]=a+b;
}
// wave-aggregated: ONE atomic per wave per type. Order within a type
// bucket is arbitrary by construction, so ballot-rank placement is valid.
__global__ void k_nb_scatter(const int* __restrict__ ntype, const int* __restrict__ boff,
                             int* __restrict__ bcur, int* __restrict__ perm){
  int n = blockIdx.x*256 + threadIdx.x;
  int t = (n < NN) ? ntype[n] : -1;
  int lane = threadIdx.x & 63;
  #pragma unroll
  for(int tt=0; tt<3; tt++){
    unsigned long long mask = __ballot(t == tt);
    if(t == tt){
      int rank = __popcll(mask & ((1ull<<lane)-1ull));
      int leader = __ffsll((long long)mask) - 1;
      int base = 0;
      if(lane == leader) base = atomicAdd(&bcur[tt], __popcll(mask));
      base = __shfl(base, leader);
      perm[boff[tt] + base + rank] = n;
    }
  }
}

// ---------------- CSR by dst ----------------
__global__ void k_deg(const int* __restrict__ ei, int* __restrict__ deg){
  int e = blockIdx.x*256 + threadIdx.x;
  if(e < NE) atomicAdd(&deg[ei[NE + e]], 1);
}
__global__ void k_scan(const int* __restrict__ deg, int* __restrict__ row_off){
  __shared__ int sums[1024];
  int t = threadIdx.x;
  const int CH = 20;                 // 1024*20 >= NN
  int local[CH];
  int s = 0;
  #pragma unroll
  for(int j=0;j<CH;j++){
    int i = t*CH + j;
    local[j] = s;
    s += (i < NN) ? deg[i] : 0;
  }
  sums[t] = s;
  __syncthreads();
  for(int off=1; off<1024; off<<=1){
    int v = (t>=off) ? sums[t-off] : 0;
    __syncthreads();
    if(t>=off) sums[t] += v;
    __syncthreads();
  }
  int base = (t==0) ? 0 : sums[t-1];
  #pragma unroll
  for(int j=0;j<CH;j++){
    int i = t*CH + j;
    if(i < NN) row_off[i] = base + local[j];
  }
  if(t==1023) row_off[NN] = sums[1023];
}
__global__ void k_escatter(const int* __restrict__ ei, const int* __restrict__ etype,
                           const int* __restrict__ row_off, int* __restrict__ cursor,
                           int* __restrict__ packed){
  int e = blockIdx.x*256 + threadIdx.x;
  if(e < NE){
    int dst = ei[NE+e];
    int pos = row_off[dst] + atomicAdd(&cursor[dst],1);
    packed[pos] = ei[e] | (etype[e] << 20);   // src < 2^20, r in bits 20..22
  }
}

// ---------------- prep: cast x -> bf16 ----------------
__global__ void k_castx(const float* __restrict__ x, u16* __restrict__ xb){
  int i = blockIdx.x*256 + threadIdx.x;     // 8 floats per thread; 2500 blocks
  float4 v0 = ((const float4*)x)[i*2+0];
  float4 v1 = ((const float4*)x)[i*2+1];
  uint4 o;
  o.x = (u32)f2bf(v0.x) | ((u32)f2bf(v0.y)<<16);
  o.y = (u32)f2bf(v0.z) | ((u32)f2bf(v0.w)<<16);
  o.z = (u32)f2bf(v1.x) | ((u32)f2bf(v1.y)<<16);
  o.w = (u32)f2bf(v1.z) | ((u32)f2bf(v1.w)<<16);
  ((uint4*)xb)[i] = o;
}

// ---------------- prep: transpose + cast Wk/Wq/Wv -> bf16 [t][out][in] ----------------
__global__ __launch_bounds__(256) void k_castw(
  const float* __restrict__ Wk, const float* __restrict__ Wq, const float* __restrict__ Wv,
  u16* __restrict__ Wtk, u16* __restrict__ Wtq, u16* __restrict__ Wtv)
{
  __shared__ float tile[32][33];
  int z = blockIdx.z;                       // 0..8: tensor*3 + t
  int tensor = z/3, t = z%3;
  const float* W = (tensor==0) ? Wk : (tensor==1) ? Wq : Wv;
  u16* O = (tensor==0) ? Wtk : (tensor==1) ? Wtq : Wtv;
  int i0 = blockIdx.x*32, j0 = blockIdx.y*32;
  int rr = threadIdx.x>>5, cc = threadIdx.x&31;
  #pragma unroll
  for(int p=0;p<4;p++)
    tile[rr+p*8][cc] = W[t*65536 + (i0+rr+p*8)*256 + j0+cc];
  __syncthreads();
  #pragma unroll
  for(int p=0;p<4;p++)
    O[t*65536 + (j0+rr+p*8)*256 + i0+cc] = f2bf(tile[cc][rr+p*8]);
}

// ---------------- typed K/Q/V projections via MFMA 16x16x32 bf16 ----------------
__global__ __launch_bounds__(256) void k_proj(
    const u16* __restrict__ xb, const int* __restrict__ perm, const int* __restrict__ boff,
    const u16* __restrict__ Wtk, const u16* __restrict__ Wtq, const u16* __restrict__ Wtv,
    const float* __restrict__ bk, const float* __restrict__ bq, const float* __restrict__ bv,
    u16* __restrict__ Kn, float* __restrict__ Qn, u16* __restrict__ Vn)
{
  __shared__ u16 xs[32*DD];
  __shared__ int gids[32];
  int tid = threadIdx.x;
  int ts = blockIdx.x*32;
  int t = (ts >= boff[2]) ? 2 : (ts >= boff[1]) ? 1 : 0;   // boff 32-aligned
  if(tid < 32) gids[tid] = perm[ts + tid];
  __syncthreads();
  #pragma unroll
  for(int it=0; it<4; it++){
    int q = tid + it*256;
    int row = q >> 5, c = q & 31;
    int g = gids[row];
    uint4 v = make_uint4(0,0,0,0);
    if(g >= 0) v = ((const uint4*)(xb + (size_t)g*DD))[c];
    ((uint4*)xs)[q] = v;
  }
  __syncthreads();
  int lane = tid & 63;
  int w = tid >> 6;
  int quad = lane >> 4;
  int l16 = lane & 15;
  f32x4 accK[2][4], accQ[2][4], accV[2][4];
  #pragma unroll
  for(int mt=0;mt<2;mt++)
    #pragma unroll
    for(int nt=0;nt<4;nt++){
      accK[mt][nt]=(f32x4)(0.f); accQ[mt][nt]=(f32x4)(0.f); accV[mt][nt]=(f32x4)(0.f);
    }
  const u16* wkp = Wtk + (size_t)t*65536;
  const u16* wqp = Wtq + (size_t)t*65536;
  const u16* wvp = Wtv + (size_t)t*65536;
  #pragma unroll
  for(int kk=0; kk<8; kk++){
    int kb = kk*32 + quad*8;
    bf16x8 a0 = *(const bf16x8*)(xs + l16*DD + kb);
    bf16x8 a1 = *(const bf16x8*)(xs + (16+l16)*DD + kb);
    #pragma unroll
    for(int nt=0; nt<4; nt++){
      int n = w*64 + nt*16 + l16;
      bf16x8 bK = *(const bf16x8*)(wkp + (size_t)n*DD + kb);
      bf16x8 bQ = *(const bf16x8*)(wqp + (size_t)n*DD + kb);
      bf16x8 bV = *(const bf16x8*)(wvp + (size_t)n*DD + kb);
      accK[0][nt] = __builtin_amdgcn_mfma_f32_16x16x32_bf16(a0, bK, accK[0][nt], 0,0,0);
      accK[1][nt] = __builtin_amdgcn_mfma_f32_16x16x32_bf16(a1, bK, accK[1][nt], 0,0,0);
      accQ[0][nt] = __builtin_amdgcn_mfma_f32_16x16x32_bf16(a0, bQ, accQ[0][nt], 0,0,0);
      accQ[1][nt] = __builtin_amdgcn_mfma_f32_16x16x32_bf16(a1, bQ, accQ[1][nt], 0,0,0);
      accV[0][nt] = __builtin_amdgcn_mfma_f32_16x16x32_bf16(a0, bV, accV[0][nt], 0,0,0);
      accV[1][nt] = __builtin_amdgcn_mfma_f32_16x16x32_bf16(a1, bV, accV[1][nt], 0,0,0);
    }
  }
  #pragma unroll
  for(int nt=0; nt<4; nt++){
    int colg = w*64 + nt*16 + l16;
    float bkv = bk[t*DD+colg], bqv = bq[t*DD+colg], bvv = bv[t*DD+colg];
    #pragma unroll
    for(int mt=0; mt<2; mt++){
      #pragma unroll
      for(int reg=0; reg<4; reg++){
        int row = mt*16 + quad*4 + reg;
        int g = gids[row];
        if(g >= 0){
          Kn[(size_t)g*DD + colg] = f2bf(accK[mt][nt][reg] + bkv);
          Qn[(size_t)g*DD + colg] = accQ[mt][nt][reg] + bqv;
          Vn[(size_t)g*DD + colg] = f2bf(accV[mt][nt][reg] + bvv);
        }
      }
    }
  }
}

// ---------------- QA[n,r,h,k] = (prior/sqrtK) * sum_l A[r,h,k,l]*Qn[n,h,l] ----------------
__global__ __launch_bounds__(256) void k_qa(
    const float* __restrict__ Qn, const float* __restrict__ rel_att,
    const float* __restrict__ rel_prior, u16* __restrict__ QA)
{
  __shared__ float At[NH*KK*33];    // [h][l][k], padded to kill bank conflicts
  __shared__ float qs[16*DD];
  int tid = threadIdx.x;
  int r = blockIdx.y;
  int n0 = blockIdx.x * 16;
  const float* A = rel_att + r*NH*KK*KK;
  #pragma unroll
  for(int it=0; it<32; it++){
    int idx = tid + it*256;
    int h = idx >> 10, k = (idx >> 5) & 31, l = idx & 31;
    At[(h*KK + l)*33 + k] = A[idx];
  }
  #pragma unroll
  for(int it=0; it<4; it++){
    int f4 = tid + it*256;
    ((float4*)qs)[f4] = ((const float4*)(Qn + (size_t)n0*DD))[f4];
  }
  __syncthreads();
  int h = tid >> 5, k = tid & 31;
  float areg[KK];
  #pragma unroll
  for(int l=0;l<KK;l++) areg[l] = At[(h*KK + l)*33 + k];
  float scale = rel_prior[r*NH + h] * 0.17677669529663687f;  // 1/sqrt(32)
  for(int n=0;n<16;n++){
    float s = 0.f;
    #pragma unroll
    for(int l4=0;l4<8;l4++){
      float4 q = ((const float4*)(qs + n*DD + h*KK))[l4];
      s += areg[l4*4+0]*q.x + areg[l4*4+1]*q.y + areg[l4*4+2]*q.z + areg[l4*4+3]*q.w;
    }
    QA[((size_t)(n0+n)*NR + r)*DD + tid] = f2bf(s*scale);
  }
}

// ---------------- fused per-node softmax + aggregation (wave per node, no atomics) --------
__global__ __launch_bounds__(256) void k_edge(
    const u16* __restrict__ Kn, const u16* __restrict__ Vn, const u16* __restrict__ QA,
    const int* __restrict__ row_off, const int* __restrict__ packed,
    u16* __restrict__ aggrV)
{
  int lane = threadIdx.x & 63;
  int n = blockIdx.x*4 + (threadIdx.x >> 6);
  if(n >= NN) return;
  int off = lane*4;                  // = h*32 + j*4 with h=lane>>3
  float4 qa0,qa1,qa2,qa3,qa4;
  {
    const u16* qp = QA + (size_t)n*NR*DD + off;
    ushort4 q;
    q = *(const ushort4*)(qp + 0*DD); qa0 = make_float4(bf2f(q.x),bf2f(q.y),bf2f(q.z),bf2f(q.w));
    q = *(const ushort4*)(qp + 1*DD); qa1 = make_float4(bf2f(q.x),bf2f(q.y),bf2f(q.z),bf2f(q.w));
    q = *(const ushort4*)(qp + 2*DD); qa2 = make_float4(bf2f(q.x),bf2f(q.y),bf2f(q.z),bf2f(q.w));
    q = *(const ushort4*)(qp + 3*DD); qa3 = make_float4(bf2f(q.x),bf2f(q.y),bf2f(q.z),bf2f(q.w));
    q = *(const ushort4*)(qp + 4*DD); qa4 = make_float4(bf2f(q.x),bf2f(q.y),bf2f(q.z),bf2f(q.w));
  }
  float4 a0=make_float4(0,0,0,0), a1=a0, a2=a0, a3=a0, a4=a0;
  float s = 0.f;
  int e0 = row_off[n], e1 = row_off[n+1];
  for(int e=e0; e<e1; e++){
    int pk = packed[e];              // wave-uniform
    int src = pk & 0xFFFFF;
    int r = pk >> 20;
    ushort4 ku = *(const ushort4*)(Kn + (size_t)src*DD + off);
    ushort4 vu = *(const ushort4*)(Vn + (size_t)src*DD + off);
    float4 kv = make_float4(bf2f(ku.x),bf2f(ku.y),bf2f(ku.z),bf2f(ku.w));
    float4 vv = make_float4(bf2f(vu.x),bf2f(vu.y),bf2f(vu.z),bf2f(vu.w));
    float4 q;
    switch(r){ case 0: q=qa0; break; case 1: q=qa1; break; case 2: q=qa2; break;
               case 3: q=qa3; break; default: q=qa4; }
    float d = kv.x*q.x + kv.y*q.y + kv.z*q.z + kv.w*q.w;
    d += __shfl_xor(d, 1);           // butterfly within the 8-lane head group
    d += __shfl_xor(d, 2);
    d += __shfl_xor(d, 4);
    float p = __expf(d);             // no max-subtract: logits ~O(1), fp32-safe
    s += p;
    switch(r){
      case 0: a0.x+=p*vv.x; a0.y+=p*vv.y; a0.z+=p*vv.z; a0.w+=p*vv.w; break;
      case 1: a1.x+=p*vv.x; a1.y+=p*vv.y; a1.z+=p*vv.z; a1.w+=p*vv.w; break;
      case 2: a2.x+=p*vv.x; a2.y+=p*vv.y; a2.z+=p*vv.z; a2.w+=p*vv.w; break;
      case 3: a3.x+=p*vv.x; a3.y+=p*vv.y; a3.z+=p*vv.z; a3.w+=p*vv.w; break;
      default:a4.x+=p*vv.x; a4.y+=p*vv.y; a4.z+=p*vv.z; a4.w+=p*vv.w; break;
    }
  }
  float inv = (s > 0.f) ? (1.f/s) : 0.f;
  u16* op = aggrV + (size_t)n*NR*DD + off;
  #define ST(ptr, a) { ushort4 o; o.x=f2bf((a).x*inv); o.y=f2bf((a).y*inv); \
                       o.z=f2bf((a).z*inv); o.w=f2bf((a).w*inv); *(ushort4*)(ptr)=o; }
  ST(op + 0*DD, a0); ST(op + 1*DD, a1); ST(op + 2*DD, a2); ST(op + 3*DD, a3); ST(op + 4*DD, a4);
  #undef ST
}

// ---------------- apply rel_msg per (node, r), sum over r, ELU ----------------
__global__ __launch_bounds__(256) void k_msg(
    const u16* __restrict__ aggrV, const float* __restrict__ rel_msg,
    float* __restrict__ h1)
{
  __shared__ float Ms[NH*KK*KK];     // [h][k][l]
  __shared__ ushort4 Vs[32*64];      // 32 nodes x 256 bf16
  int tid = threadIdx.x;
  int n0 = blockIdx.x*32;
  int h = tid >> 5, l = tid & 31;
  float acc[32];
  #pragma unroll
  for(int n=0;n<32;n++) acc[n]=0.f;
  for(int r=0;r<NR;r++){
    #pragma unroll
    for(int it=0; it<32; it++){
      int idx = tid + it*256;
      Ms[idx] = rel_msg[r*8192 + idx];
    }
    #pragma unroll
    for(int it=0; it<8; it++){
      int f4 = tid + it*256;
      int row = f4 >> 6, c4 = f4 & 63;
      Vs[f4] = ((const ushort4*)(aggrV + ((size_t)(n0+row)*NR + r)*DD))[c4];
    }
    __syncthreads();
    float mreg[KK];
    #pragma unroll
    for(int k=0;k<KK;k++) mreg[k] = Ms[h*1024 + k*KK + l];
    for(int n=0;n<32;n++){
      #pragma unroll
      for(int k4=0;k4<8;k4++){
        ushort4 v = Vs[n*64 + h*8 + k4];
        acc[n] += mreg[k4*4+0]*bf2f(v.x) + mreg[k4*4+1]*bf2f(v.y)
                + mreg[k4*4+2]*bf2f(v.z) + mreg[k4*4+3]*bf2f(v.w);
      }
    }
    __syncthreads();
  }
  for(int n=0;n<32;n++){
    float v = acc[n];
    v = (v > 0.f) ? v : expm1f(v);
    h1[(size_t)(n0+n)*DD + tid] = v;
  }
}

// ---------------- typed Wa + residual + classifier + log_softmax ----------------
__global__ __launch_bounds__(256) void k_out(
    const float* __restrict__ h1, const float* __restrict__ x,
    const int* __restrict__ perm, const int* __restrict__ boff,
    const float* __restrict__ Wa, const float* __restrict__ ba,
    const float* __restrict__ Wo, const float* __restrict__ bo,
    float* __restrict__ out)
{
  __shared__ float hs[32*DD];
  __shared__ float wo[DD*NC];
  __shared__ float cls[32*NC];
  __shared__ int gids[32];
  int tid = threadIdx.x;
  int ts = blockIdx.x*32;
  int t = (ts >= boff[2]) ? 2 : (ts >= boff[1]) ? 1 : 0;
  if(tid < 32) gids[tid] = perm[ts + tid];
  #pragma unroll
  for(int it=0; it<16; it++) wo[tid + it*256] = Wo[tid + it*256];
  __syncthreads();
  #pragma unroll
  for(int it=0; it<8; it++){
    int f4 = tid + it*256;
    int row = f4 >> 6, c4 = f4 & 63;
    int g = gids[row];
    float4 v = make_float4(0.f,0.f,0.f,0.f);
    if(g >= 0) v = ((const float4*)(h1 + (size_t)g*DD))[c4];
    ((float4*)hs)[f4] = v;
  }
  __syncthreads();
  float acc[32];
  #pragma unroll
  for(int n=0;n<32;n++) acc[n]=0.f;
  const float* wa = Wa + t*65536 + tid;
  for(int i=0;i<DD;i+=4){
    float w0=wa[(i+0)*DD], w1=wa[(i+1)*DD], w2=wa[(i+2)*DD], w3=wa[(i+3)*DD];
    #pragma unroll
    for(int n=0;n<32;n++){
      float4 xv = ((const float4*)(hs + n*DD))[i>>2];
      acc[n] += xv.x*w0 + xv.y*w1 + xv.z*w2 + xv.w*w3;
    }
  }
  float bav = ba[t*DD + tid];
  float h2v[32];
  for(int n=0;n<32;n++){
    int g = gids[n];
    float xr = (g>=0) ? x[(size_t)g*DD + tid] : 0.f;
    h2v[n] = acc[n] + bav + xr;
  }
  __syncthreads();
  for(int n=0;n<32;n++) hs[n*DD + tid] = h2v[n];
  __syncthreads();
  {
    int n = tid >> 3, q = tid & 7;
    int c0 = q*2;
    float s0 = bo[c0], s1 = bo[c0+1];
    for(int i=0;i<DD;i++){
      float hv = hs[n*DD + i];
      s0 += hv * wo[i*NC + c0];
      s1 += hv * wo[i*NC + c0 + 1];
    }
    cls[n*NC + c0] = s0;
    cls[n*NC + c0 + 1] = s1;
  }
  __syncthreads();
  if(tid < 32){
    int g = gids[tid];
    if(g >= 0){
      float m = -1e30f;
      #pragma unroll
      for(int c=0;c<NC;c++) m = fmaxf(m, cls[tid*NC + c]);
      float sum = 0.f;
      #pragma unroll
      for(int c=0;c<NC;c++) sum += __expf(cls[tid*NC + c] - m);
      float lse = m + __logf(sum);
      #pragma unroll
      for(int c=0;c<NC;c++) out[(size_t)g*NC + c] = cls[tid*NC + c] - lse;
    }
  }
}

extern "C" void kernel_launch(void* const* d_in, const int* in_sizes, int n_in,
                              void* d_out, int out_size, void* d_ws, size_t ws_size,
                              hipStream_t stream)
{
  const float* x     = (const float*)d_in[0];
  const int*   ei    = (const int*)d_in[1];
  const int*   ntype = (const int*)d_in[2];
  const int*   etype = (const int*)d_in[3];
  const float* Wk    = (const float*)d_in[4];
  const float* bk    = (const float*)d_in[5];
  const float* Wq    = (const float*)d_in[6];
  const float* bq    = (const float*)d_in[7];
  const float* Wv    = (const float*)d_in[8];
  const float* bv    = (const float*)d_in[9];
  const float* Wa    = (const float*)d_in[10];
  const float* ba    = (const float*)d_in[11];
  const float* prior = (const float*)d_in[12];
  const float* ratt  = (const float*)d_in[13];
  const float* rmsg  = (const float*)d_in[14];
  const float* Wo    = (const float*)d_in[15];
  const float* bo    = (const float*)d_in[16];
  float* out = (float*)d_out;

  char* ws = (char*)d_ws;
  int* iw      = (int*)ws;
  int* cnt     = iw + 0;
  int* bcur    = iw + 4;
  int* boff    = iw + 8;
  int* deg     = iw + 16;
  int* cursor  = iw + 16 + NN;
  int* row_off = iw + 16 + 2*NN;          // NN+1 entries
  int* perm    = iw + 60032;              // 628*32 = 20096 entries
  int* packed  = iw + 80128;              // NE entries; ends at int 400128

  size_t fb = 1600512;                    // bytes (400128 ints), 256-aligned
  float* Qn    = (float*)(ws + fb); fb += 4ull*NN*DD;
  float* h1    = (float*)(ws + fb); fb += 4ull*NN*DD;
  u16*   Kn    = (u16*)(ws + fb);   fb += 2ull*NN*DD;
  u16*   Vn    = (u16*)(ws + fb);   fb += 2ull*NN*DD;
  u16*   QA    = (u16*)(ws + fb);   fb += 2ull*NN*NR*DD;
  u16*   aggrV = (u16*)(ws + fb);   fb += 2ull*NN*NR*DD;
  // aliases: xb lives in aggrV's region (dead until k_edge),
  // transposed bf16 weights live in h1's region (dead until k_msg).
  u16* xb  = aggrV;                       // NN*DD bf16 = 10.24 MB <= 51.2 MB
  u16* Wtk = (u16*)h1;                    // 3*65536 bf16 each
  u16* Wtq = Wtk + 3*65536;
  u16* Wtv = Wtq + 3*65536;               // total 1.18 MB <= 20.48 MB

  hipMemsetAsync(iw, 0, (size_t)(16 + 2*NN)*sizeof(int), stream);      // cnt,bcur,boff,deg,cursor
  hipMemsetAsync(perm, 0xFF, (size_t)20096*sizeof(int), stream);       // perm = -1

  k_nb_count  <<<79, 256, 0, stream>>>(ntype, cnt);
  k_nb_off    <<<1, 1, 0, stream>>>(cnt, boff);
  k_nb_scatter<<<79, 256, 0, stream>>>(ntype, boff, bcur, perm);
  k_deg       <<<1250, 256, 0, stream>>>(ei, deg);
  k_scan      <<<1, 1024, 0, stream>>>(deg, row_off);
  k_escatter  <<<1250, 256, 0, stream>>>(ei, etype, row_off, cursor, packed);
  k_castx     <<<2500, 256, 0, stream>>>(x, xb);
  k_castw     <<<dim3(8,8,9), 256, 0, stream>>>(Wk, Wq, Wv, Wtk, Wtq, Wtv);
  k_proj      <<<628, 256, 0, stream>>>(xb, perm, boff, Wtk, Wtq, Wtv, bk, bq, bv, Kn, Qn, Vn);
  k_qa        <<<dim3(1250,5), 256, 0, stream>>>(Qn, ratt, prior, QA);
  k_edge      <<<5000, 256, 0, stream>>>(Kn, Vn, QA, row_off, packed, aggrV);
  k_msg       <<<625, 256, 0, stream>>>(aggrV, rmsg, h1);
  k_out       <<<628, 256, 0, stream>>>(h1, x, perm, boff, Wa, ba, Wo, bo, out);
}

// Round 6
// 495.692 us; speedup vs baseline: 1.8658x; 1.1722x over previous
//
#include <hip/hip_runtime.h>
#include <hip/hip_bf16.h>
#include <math.h>

#define NN 20000
#define NE 320000
#define DD 256
#define NH 8
#define KK 32
#define NR 5
#define NC 16

typedef unsigned short u16;
typedef unsigned int u32;
typedef __attribute__((ext_vector_type(8))) short bf16x8;
typedef __attribute__((ext_vector_type(4))) float f32x4;

__device__ __forceinline__ float bf2f(u16 v){ return __uint_as_float(((u32)v)<<16); }
__device__ __forceinline__ u16 f2bf(float f){
  u32 u = __float_as_uint(f);
  return (u16)((u + 0x7FFFu + ((u>>16)&1u)) >> 16);
}

// ---------------- node bucketing by type (for typed GEMMs) ----------------
// wave-aggregated: ONE atomic per wave per type (was: one per node -> 128us
// of same-address atomic serialization).
__global__ void k_nb_count(const int* __restrict__ ntype, int* __restrict__ cnt){
  int n = blockIdx.x*256 + threadIdx.x;
  int t = (n < NN) ? ntype[n] : -1;
  int lane = threadIdx.x & 63;
  #pragma unroll
  for(int tt=0; tt<3; tt++){
    unsigned long long mask = __ballot(t == tt);
    int leader = __ffsll((long long)mask) - 1;
    if(lane == leader) atomicAdd(&cnt[tt], __popcll(mask));
  }
}
__global__ void k_nb_off(const int* __restrict__ cnt, int* __restrict__ boff){
  int a = (cnt[0]+31)&~31;
  int b = (cnt[1]+31)&~31;
  boff[0]=0; boff[1]=a; boff[2]=a+b;
}
// wave-aggregated: ONE atomic per wave per type. Order within a type
// bucket is arbitrary by construction, so ballot-rank placement is valid.
__global__ void k_nb_scatter(const int* __restrict__ ntype, const int* __restrict__ boff,
                             int* __restrict__ bcur, int* __restrict__ perm){
  int n = blockIdx.x*256 + threadIdx.x;
  int t = (n < NN) ? ntype[n] : -1;
  int lane = threadIdx.x & 63;
  #pragma unroll
  for(int tt=0; tt<3; tt++){
    unsigned long long mask = __ballot(t == tt);
    if(t == tt){
      int rank = __popcll(mask & ((1ull<<lane)-1ull));
      int leader = __ffsll((long long)mask) - 1;
      int base = 0;
      if(lane == leader) base = atomicAdd(&bcur[tt], __popcll(mask));
      base = __shfl(base, leader);
      perm[boff[tt] + base + rank] = n;
    }
  }
}

// ---------------- CSR by dst ----------------
__global__ void k_deg(const int* __restrict__ ei, int* __restrict__ deg){
  int e = blockIdx.x*256 + threadIdx.x;
  if(e < NE) atomicAdd(&deg[ei[NE + e]], 1);
}
__global__ void k_scan(const int* __restrict__ deg, int* __restrict__ row_off){
  __shared__ int sums[1024];
  int t = threadIdx.x;
  const int CH = 20;                 // 1024*20 >= NN
  int local[CH];
  int s = 0;
  #pragma unroll
  for(int j=0;j<CH;j++){
    int i = t*CH + j;
    local[j] = s;
    s += (i < NN) ? deg[i] : 0;
  }
  sums[t] = s;
  __syncthreads();
  for(int off=1; off<1024; off<<=1){
    int v = (t>=off) ? sums[t-off] : 0;
    __syncthreads();
    if(t>=off) sums[t] += v;
    __syncthreads();
  }
  int base = (t==0) ? 0 : sums[t-1];
  #pragma unroll
  for(int j=0;j<CH;j++){
    int i = t*CH + j;
    if(i < NN) row_off[i] = base + local[j];
  }
  if(t==1023) row_off[NN] = sums[1023];
}
__global__ void k_escatter(const int* __restrict__ ei, const int* __restrict__ etype,
                           const int* __restrict__ row_off, int* __restrict__ cursor,
                           int* __restrict__ packed){
  int e = blockIdx.x*256 + threadIdx.x;
  if(e < NE){
    int dst = ei[NE+e];
    int pos = row_off[dst] + atomicAdd(&cursor[dst],1);
    packed[pos] = ei[e] | (etype[e] << 20);   // src < 2^20, r in bits 20..22
  }
}

// ---------------- prep: cast x -> bf16 ----------------
__global__ void k_castx(const float* __restrict__ x, u16* __restrict__ xb){
  int i = blockIdx.x*256 + threadIdx.x;     // 8 floats per thread; 2500 blocks
  float4 v0 = ((const float4*)x)[i*2+0];
  float4 v1 = ((const float4*)x)[i*2+1];
  uint4 o;
  o.x = (u32)f2bf(v0.x) | ((u32)f2bf(v0.y)<<16);
  o.y = (u32)f2bf(v0.z) | ((u32)f2bf(v0.w)<<16);
  o.z = (u32)f2bf(v1.x) | ((u32)f2bf(v1.y)<<16);
  o.w = (u32)f2bf(v1.z) | ((u32)f2bf(v1.w)<<16);
  ((uint4*)xb)[i] = o;
}

// ---------------- prep: transpose + cast Wk/Wq/Wv -> bf16 [t][out][in] ----------------
__global__ __launch_bounds__(256) void k_castw(
  const float* __restrict__ Wk, const float* __restrict__ Wq, const float* __restrict__ Wv,
  u16* __restrict__ Wtk, u16* __restrict__ Wtq, u16* __restrict__ Wtv)
{
  __shared__ float tile[32][33];
  int z = blockIdx.z;                       // 0..8: tensor*3 + t
  int tensor = z/3, t = z%3;
  const float* W = (tensor==0) ? Wk : (tensor==1) ? Wq : Wv;
  u16* O = (tensor==0) ? Wtk : (tensor==1) ? Wtq : Wtv;
  int i0 = blockIdx.x*32, j0 = blockIdx.y*32;
  int rr = threadIdx.x>>5, cc = threadIdx.x&31;
  #pragma unroll
  for(int p=0;p<4;p++)
    tile[rr+p*8][cc] = W[t*65536 + (i0+rr+p*8)*256 + j0+cc];
  __syncthreads();
  #pragma unroll
  for(int p=0;p<4;p++)
    O[t*65536 + (j0+rr+p*8)*256 + i0+cc] = f2bf(tile[cc][rr+p*8]);
}

// ---------------- prep: transpose + cast rel_msg [r,h,k,l] -> bf16 [r,h,l,k] ----------
__global__ void k_castm(const float* __restrict__ rmsg, u16* __restrict__ Mtm){
  int idx = blockIdx.x*256 + threadIdx.x;   // 160 blocks, 40960 elems
  int l = idx & 31, k = (idx >> 5) & 31, rh = idx >> 10;
  Mtm[(rh*32 + l)*32 + k] = f2bf(rmsg[idx]);
}

// ---------------- typed K/Q/V projections via MFMA 16x16x32 bf16 ----------------
__global__ __launch_bounds__(256) void k_proj(
    const u16* __restrict__ xb, const int* __restrict__ perm, const int* __restrict__ boff,
    const u16* __restrict__ Wtk, const u16* __restrict__ Wtq, const u16* __restrict__ Wtv,
    const float* __restrict__ bk, const float* __restrict__ bq, const float* __restrict__ bv,
    u16* __restrict__ Kn, float* __restrict__ Qn, u16* __restrict__ Vn)
{
  __shared__ u16 xs[32*DD];
  __shared__ int gids[32];
  int tid = threadIdx.x;
  int ts = blockIdx.x*32;
  int t = (ts >= boff[2]) ? 2 : (ts >= boff[1]) ? 1 : 0;   // boff 32-aligned
  if(tid < 32) gids[tid] = perm[ts + tid];
  __syncthreads();
  #pragma unroll
  for(int it=0; it<4; it++){
    int q = tid + it*256;
    int row = q >> 5, c = q & 31;
    int g = gids[row];
    uint4 v = make_uint4(0,0,0,0);
    if(g >= 0) v = ((const uint4*)(xb + (size_t)g*DD))[c];
    ((uint4*)xs)[q] = v;
  }
  __syncthreads();
  int lane = tid & 63;
  int w = tid >> 6;
  int quad = lane >> 4;
  int l16 = lane & 15;
  f32x4 accK[2][4], accQ[2][4], accV[2][4];
  #pragma unroll
  for(int mt=0;mt<2;mt++)
    #pragma unroll
    for(int nt=0;nt<4;nt++){
      accK[mt][nt]=(f32x4)(0.f); accQ[mt][nt]=(f32x4)(0.f); accV[mt][nt]=(f32x4)(0.f);
    }
  const u16* wkp = Wtk + (size_t)t*65536;
  const u16* wqp = Wtq + (size_t)t*65536;
  const u16* wvp = Wtv + (size_t)t*65536;
  #pragma unroll
  for(int kk=0; kk<8; kk++){
    int kb = kk*32 + quad*8;
    bf16x8 a0 = *(const bf16x8*)(xs + l16*DD + kb);
    bf16x8 a1 = *(const bf16x8*)(xs + (16+l16)*DD + kb);
    #pragma unroll
    for(int nt=0; nt<4; nt++){
      int n = w*64 + nt*16 + l16;
      bf16x8 bK = *(const bf16x8*)(wkp + (size_t)n*DD + kb);
      bf16x8 bQ = *(const bf16x8*)(wqp + (size_t)n*DD + kb);
      bf16x8 bV = *(const bf16x8*)(wvp + (size_t)n*DD + kb);
      accK[0][nt] = __builtin_amdgcn_mfma_f32_16x16x32_bf16(a0, bK, accK[0][nt], 0,0,0);
      accK[1][nt] = __builtin_amdgcn_mfma_f32_16x16x32_bf16(a1, bK, accK[1][nt], 0,0,0);
      accQ[0][nt] = __builtin_amdgcn_mfma_f32_16x16x32_bf16(a0, bQ, accQ[0][nt], 0,0,0);
      accQ[1][nt] = __builtin_amdgcn_mfma_f32_16x16x32_bf16(a1, bQ, accQ[1][nt], 0,0,0);
      accV[0][nt] = __builtin_amdgcn_mfma_f32_16x16x32_bf16(a0, bV, accV[0][nt], 0,0,0);
      accV[1][nt] = __builtin_amdgcn_mfma_f32_16x16x32_bf16(a1, bV, accV[1][nt], 0,0,0);
    }
  }
  #pragma unroll
  for(int nt=0; nt<4; nt++){
    int colg = w*64 + nt*16 + l16;
    float bkv = bk[t*DD+colg], bqv = bq[t*DD+colg], bvv = bv[t*DD+colg];
    #pragma unroll
    for(int mt=0; mt<2; mt++){
      #pragma unroll
      for(int reg=0; reg<4; reg++){
        int row = mt*16 + quad*4 + reg;
        int g = gids[row];
        if(g >= 0){
          Kn[(size_t)g*DD + colg] = f2bf(accK[mt][nt][reg] + bkv);
          Qn[(size_t)g*DD + colg] = accQ[mt][nt][reg] + bqv;
          Vn[(size_t)g*DD + colg] = f2bf(accV[mt][nt][reg] + bvv);
        }
      }
    }
  }
}

// ---------------- QA[n,r,h,k] = (prior/sqrtK) * sum_l A[r,h,k,l]*Qn[n,h,l] ----------------
__global__ __launch_bounds__(256) void k_qa(
    const float* __restrict__ Qn, const float* __restrict__ rel_att,
    const float* __restrict__ rel_prior, u16* __restrict__ QA)
{
  __shared__ float At[NH*KK*33];    // [h][l][k], padded to kill bank conflicts
  __shared__ float qs[16*DD];
  int tid = threadIdx.x;
  int r = blockIdx.y;
  int n0 = blockIdx.x * 16;
  const float* A = rel_att + r*NH*KK*KK;
  #pragma unroll
  for(int it=0; it<32; it++){
    int idx = tid + it*256;
    int h = idx >> 10, k = (idx >> 5) & 31, l = idx & 31;
    At[(h*KK + l)*33 + k] = A[idx];
  }
  #pragma unroll
  for(int it=0; it<4; it++){
    int f4 = tid + it*256;
    ((float4*)qs)[f4] = ((const float4*)(Qn + (size_t)n0*DD))[f4];
  }
  __syncthreads();
  int h = tid >> 5, k = tid & 31;
  float areg[KK];
  #pragma unroll
  for(int l=0;l<KK;l++) areg[l] = At[(h*KK + l)*33 + k];
  float scale = rel_prior[r*NH + h] * 0.17677669529663687f;  // 1/sqrt(32)
  for(int n=0;n<16;n++){
    float s = 0.f;
    #pragma unroll
    for(int l4=0;l4<8;l4++){
      float4 q = ((const float4*)(qs + n*DD + h*KK))[l4];
      s += areg[l4*4+0]*q.x + areg[l4*4+1]*q.y + areg[l4*4+2]*q.z + areg[l4*4+3]*q.w;
    }
    QA[((size_t)(n0+n)*NR + r)*DD + tid] = f2bf(s*scale);
  }
}

// ---------------- fused per-node softmax + aggregation (wave per node, no atomics) --------
__global__ __launch_bounds__(256) void k_edge(
    const u16* __restrict__ Kn, const u16* __restrict__ Vn, const u16* __restrict__ QA,
    const int* __restrict__ row_off, const int* __restrict__ packed,
    u16* __restrict__ aggrV)
{
  int lane = threadIdx.x & 63;
  int n = blockIdx.x*4 + (threadIdx.x >> 6);
  if(n >= NN) return;
  int off = lane*4;                  // = h*32 + j*4 with h=lane>>3
  float4 qa0,qa1,qa2,qa3,qa4;
  {
    const u16* qp = QA + (size_t)n*NR*DD + off;
    ushort4 q;
    q = *(const ushort4*)(qp + 0*DD); qa0 = make_float4(bf2f(q.x),bf2f(q.y),bf2f(q.z),bf2f(q.w));
    q = *(const ushort4*)(qp + 1*DD); qa1 = make_float4(bf2f(q.x),bf2f(q.y),bf2f(q.z),bf2f(q.w));
    q = *(const ushort4*)(qp + 2*DD); qa2 = make_float4(bf2f(q.x),bf2f(q.y),bf2f(q.z),bf2f(q.w));
    q = *(const ushort4*)(qp + 3*DD); qa3 = make_float4(bf2f(q.x),bf2f(q.y),bf2f(q.z),bf2f(q.w));
    q = *(const ushort4*)(qp + 4*DD); qa4 = make_float4(bf2f(q.x),bf2f(q.y),bf2f(q.z),bf2f(q.w));
  }
  float4 a0=make_float4(0,0,0,0), a1=a0, a2=a0, a3=a0, a4=a0;
  float s = 0.f;
  int e0 = row_off[n], e1 = row_off[n+1];
  for(int e=e0; e<e1; e++){
    int pk = packed[e];              // wave-uniform
    int src = pk & 0xFFFFF;
    int r = pk >> 20;
    ushort4 ku = *(const ushort4*)(Kn + (size_t)src*DD + off);
    ushort4 vu = *(const ushort4*)(Vn + (size_t)src*DD + off);
    float4 kv = make_float4(bf2f(ku.x),bf2f(ku.y),bf2f(ku.z),bf2f(ku.w));
    float4 vv = make_float4(bf2f(vu.x),bf2f(vu.y),bf2f(vu.z),bf2f(vu.w));
    float4 q;
    switch(r){ case 0: q=qa0; break; case 1: q=qa1; break; case 2: q=qa2; break;
               case 3: q=qa3; break; default: q=qa4; }
    float d = kv.x*q.x + kv.y*q.y + kv.z*q.z + kv.w*q.w;
    d += __shfl_xor(d, 1);           // butterfly within the 8-lane head group
    d += __shfl_xor(d, 2);
    d += __shfl_xor(d, 4);
    float p = __expf(d);             // no max-subtract: logits ~O(1), fp32-safe
    s += p;
    switch(r){
      case 0: a0.x+=p*vv.x; a0.y+=p*vv.y; a0.z+=p*vv.z; a0.w+=p*vv.w; break;
      case 1: a1.x+=p*vv.x; a1.y+=p*vv.y; a1.z+=p*vv.z; a1.w+=p*vv.w; break;
      case 2: a2.x+=p*vv.x; a2.y+=p*vv.y; a2.z+=p*vv.z; a2.w+=p*vv.w; break;
      case 3: a3.x+=p*vv.x; a3.y+=p*vv.y; a3.z+=p*vv.z; a3.w+=p*vv.w; break;
      default:a4.x+=p*vv.x; a4.y+=p*vv.y; a4.z+=p*vv.z; a4.w+=p*vv.w; break;
    }
  }
  float inv = (s > 0.f) ? (1.f/s) : 0.f;
  u16* op = aggrV + (size_t)n*NR*DD + off;
  #define ST(ptr, a) { ushort4 o; o.x=f2bf((a).x*inv); o.y=f2bf((a).y*inv); \
                       o.z=f2bf((a).z*inv); o.w=f2bf((a).w*inv); *(ushort4*)(ptr)=o; }
  ST(op + 0*DD, a0); ST(op + 1*DD, a1); ST(op + 2*DD, a2); ST(op + 3*DD, a3); ST(op + 4*DD, a4);
  #undef ST
}

// ---------------- apply rel_msg per (node, r) via MFMA, sum over r, ELU ----------------
// h1[n, h*32+l] = ELU( sum_r sum_k aggrV[n,r,h,k] * M[r,h,k,l] )
// Block: 32 nodes, 4 waves x 2 heads each. B from pre-transposed bf16 Mtm[r,h,l,k].
#define VSP 264   // padded node row (bf16): 256 + 8 -> 2-way LDS aliasing only (free)
__global__ __launch_bounds__(256) void k_msg(
    const u16* __restrict__ aggrV, const u16* __restrict__ Mtm,
    float* __restrict__ h1)
{
  __shared__ u16 Vs[32*VSP];
  int tid = threadIdx.x;
  int n0 = blockIdx.x*32;
  int lane = tid & 63;
  int w = tid >> 6;
  int quad = lane >> 4;
  int l16 = lane & 15;
  f32x4 acc[2][2][2];   // [head][mtile][ntile]
  #pragma unroll
  for(int hh=0;hh<2;hh++)
    #pragma unroll
    for(int mt=0;mt<2;mt++)
      #pragma unroll
      for(int nt=0;nt<2;nt++) acc[hh][mt][nt]=(f32x4)(0.f);
  for(int r=0;r<NR;r++){
    __syncthreads();
    // 32 rows x 256 bf16 = 32 uint4 per row -> 1024 uint4 total (it<4)
    // (R5 bug: it<2 covered only half of each row -> NaN from poisoned LDS)
    #pragma unroll
    for(int it=0; it<4; it++){
      int q = tid + it*256;
      int row = q >> 5, c = q & 31;
      ((uint4*)(Vs + row*VSP))[c] =
        ((const uint4*)(aggrV + ((size_t)(n0+row)*NR + r)*DD))[c];
    }
    __syncthreads();
    #pragma unroll
    for(int hh=0; hh<2; hh++){
      int h = w*2 + hh;
      bf16x8 a0 = *(const bf16x8*)(Vs + l16*VSP + h*32 + quad*8);
      bf16x8 a1 = *(const bf16x8*)(Vs + (16+l16)*VSP + h*32 + quad*8);
      const u16* mp = Mtm + ((size_t)(r*NH + h)*32)*32;
      bf16x8 b0 = *(const bf16x8*)(mp + l16*32 + quad*8);
      bf16x8 b1 = *(const bf16x8*)(mp + (16+l16)*32 + quad*8);
      acc[hh][0][0] = __builtin_amdgcn_mfma_f32_16x16x32_bf16(a0, b0, acc[hh][0][0], 0,0,0);
      acc[hh][0][1] = __builtin_amdgcn_mfma_f32_16x16x32_bf16(a0, b1, acc[hh][0][1], 0,0,0);
      acc[hh][1][0] = __builtin_amdgcn_mfma_f32_16x16x32_bf16(a1, b0, acc[hh][1][0], 0,0,0);
      acc[hh][1][1] = __builtin_amdgcn_mfma_f32_16x16x32_bf16(a1, b1, acc[hh][1][1], 0,0,0);
    }
  }
  #pragma unroll
  for(int hh=0; hh<2; hh++){
    int h = w*2 + hh;
    #pragma unroll
    for(int mt=0; mt<2; mt++){
      #pragma unroll
      for(int nt=0; nt<2; nt++){
        #pragma unroll
        for(int reg=0; reg<4; reg++){
          int n = n0 + mt*16 + quad*4 + reg;
          float v = acc[hh][mt][nt][reg];
          v = (v > 0.f) ? v : expm1f(v);
          h1[(size_t)n*DD + h*32 + nt*16 + l16] = v;
        }
      }
    }
  }
}

// ---------------- typed Wa + residual + classifier + log_softmax ----------------
__global__ __launch_bounds__(256) void k_out(
    const float* __restrict__ h1, const float* __restrict__ x,
    const int* __restrict__ perm, const int* __restrict__ boff,
    const float* __restrict__ Wa, const float* __restrict__ ba,
    const float* __restrict__ Wo, const float* __restrict__ bo,
    float* __restrict__ out)
{
  __shared__ float hs[32*DD];
  __shared__ float wo[DD*NC];
  __shared__ float cls[32*NC];
  __shared__ int gids[32];
  int tid = threadIdx.x;
  int ts = blockIdx.x*32;
  int t = (ts >= boff[2]) ? 2 : (ts >= boff[1]) ? 1 : 0;
  if(tid < 32) gids[tid] = perm[ts + tid];
  #pragma unroll
  for(int it=0; it<16; it++) wo[tid + it*256] = Wo[tid + it*256];
  __syncthreads();
  #pragma unroll
  for(int it=0; it<8; it++){
    int f4 = tid + it*256;
    int row = f4 >> 6, c4 = f4 & 63;
    int g = gids[row];
    float4 v = make_float4(0.f,0.f,0.f,0.f);
    if(g >= 0) v = ((const float4*)(h1 + (size_t)g*DD))[c4];
    ((float4*)hs)[f4] = v;
  }
  __syncthreads();
  float acc[32];
  #pragma unroll
  for(int n=0;n<32;n++) acc[n]=0.f;
  const float* wa = Wa + t*65536 + tid;
  for(int i=0;i<DD;i+=4){
    float w0=wa[(i+0)*DD], w1=wa[(i+1)*DD], w2=wa[(i+2)*DD], w3=wa[(i+3)*DD];
    #pragma unroll
    for(int n=0;n<32;n++){
      float4 xv = ((const float4*)(hs + n*DD))[i>>2];
      acc[n] += xv.x*w0 + xv.y*w1 + xv.z*w2 + xv.w*w3;
    }
  }
  float bav = ba[t*DD + tid];
  float h2v[32];
  for(int n=0;n<32;n++){
    int g = gids[n];
    float xr = (g>=0) ? x[(size_t)g*DD + tid] : 0.f;
    h2v[n] = acc[n] + bav + xr;
  }
  __syncthreads();
  for(int n=0;n<32;n++) hs[n*DD + tid] = h2v[n];
  __syncthreads();
  {
    int n = tid >> 3, q = tid & 7;
    int c0 = q*2;
    float s0 = bo[c0], s1 = bo[c0+1];
    for(int i=0;i<DD;i++){
      float hv = hs[n*DD + i];
      s0 += hv * wo[i*NC + c0];
      s1 += hv * wo[i*NC + c0 + 1];
    }
    cls[n*NC + c0] = s0;
    cls[n*NC + c0 + 1] = s1;
  }
  __syncthreads();
  if(tid < 32){
    int g = gids[tid];
    if(g >= 0){
      float m = -1e30f;
      #pragma unroll
      for(int c=0;c<NC;c++) m = fmaxf(m, cls[tid*NC + c]);
      float sum = 0.f;
      #pragma unroll
      for(int c=0;c<NC;c++) sum += __expf(cls[tid*NC + c] - m);
      float lse = m + __logf(sum);
      #pragma unroll
      for(int c=0;c<NC;c++) out[(size_t)g*NC + c] = cls[tid*NC + c] - lse;
    }
  }
}

extern "C" void kernel_launch(void* const* d_in, const int* in_sizes, int n_in,
                              void* d_out, int out_size, void* d_ws, size_t ws_size,
                              hipStream_t stream)
{
  const float* x     = (const float*)d_in[0];
  const int*   ei    = (const int*)d_in[1];
  const int*   ntype = (const int*)d_in[2];
  const int*   etype = (const int*)d_in[3];
  const float* Wk    = (const float*)d_in[4];
  const float* bk    = (const float*)d_in[5];
  const float* Wq    = (const float*)d_in[6];
  const float* bq    = (const float*)d_in[7];
  const float* Wv    = (const float*)d_in[8];
  const float* bv    = (const float*)d_in[9];
  const float* Wa    = (const float*)d_in[10];
  const float* ba    = (const float*)d_in[11];
  const float* prior = (const float*)d_in[12];
  const float* ratt  = (const float*)d_in[13];
  const float* rmsg  = (const float*)d_in[14];
  const float* Wo    = (const float*)d_in[15];
  const float* bo    = (const float*)d_in[16];
  float* out = (float*)d_out;

  char* ws = (char*)d_ws;
  int* iw      = (int*)ws;
  int* cnt     = iw + 0;
  int* bcur    = iw + 4;
  int* boff    = iw + 8;
  int* deg     = iw + 16;
  int* cursor  = iw + 16 + NN;
  int* row_off = iw + 16 + 2*NN;          // NN+1 entries
  int* perm    = iw + 60032;              // 628*32 = 20096 entries
  int* packed  = iw + 80128;              // NE entries; ends at int 400128

  size_t fb = 1600512;                    // bytes (400128 ints), 256-aligned
  float* Qn    = (float*)(ws + fb); fb += 4ull*NN*DD;
  float* h1    = (float*)(ws + fb); fb += 4ull*NN*DD;
  u16*   Kn    = (u16*)(ws + fb);   fb += 2ull*NN*DD;
  u16*   Vn    = (u16*)(ws + fb);   fb += 2ull*NN*DD;
  u16*   QA    = (u16*)(ws + fb);   fb += 2ull*NN*NR*DD;
  u16*   aggrV = (u16*)(ws + fb);   fb += 2ull*NN*NR*DD;
  // aliases (no footprint growth past the validated 165.5 MB):
  //   xb  -> aggrV region (dead until k_edge)
  //   Wt* -> h1 region (dead until k_msg)
  //   Mtm -> deg/cursor region (dead after k_escatter; k_castm launched after it)
  u16* xb  = aggrV;                       // NN*DD bf16 = 10.24 MB <= 51.2 MB
  u16* Wtk = (u16*)h1;                    // 3*65536 bf16 each
  u16* Wtq = Wtk + 3*65536;
  u16* Wtv = Wtq + 3*65536;               // total 1.18 MB <= 20.48 MB
  u16* Mtm = (u16*)(iw + 16);             // 40960 bf16 = 80 KB <= 156 KB (deg+cursor)

  hipMemsetAsync(iw, 0, (size_t)(16 + 2*NN)*sizeof(int), stream);      // cnt,bcur,boff,deg,cursor
  hipMemsetAsync(perm, 0xFF, (size_t)20096*sizeof(int), stream);       // perm = -1

  k_nb_count  <<<79, 256, 0, stream>>>(ntype, cnt);
  k_nb_off    <<<1, 1, 0, stream>>>(cnt, boff);
  k_nb_scatter<<<79, 256, 0, stream>>>(ntype, boff, bcur, perm);
  k_deg       <<<1250, 256, 0, stream>>>(ei, deg);
  k_scan      <<<1, 1024, 0, stream>>>(deg, row_off);
  k_escatter  <<<1250, 256, 0, stream>>>(ei, etype, row_off, cursor, packed);
  k_castm     <<<160, 256, 0, stream>>>(rmsg, Mtm);   // after k_escatter: reuses deg/cursor ints
  k_castx     <<<2500, 256, 0, stream>>>(x, xb);
  k_castw     <<<dim3(8,8,9), 256, 0, stream>>>(Wk, Wq, Wv, Wtk, Wtq, Wtv);
  k_proj      <<<628, 256, 0, stream>>>(xb, perm, boff, Wtk, Wtq, Wtv, bk, bq, bv, Kn, Qn, Vn);
  k_qa        <<<dim3(1250,5), 256, 0, stream>>>(Qn, ratt, prior, QA);
  k_edge      <<<5000, 256, 0, stream>>>(Kn, Vn, QA, row_off, packed, aggrV);
  k_msg       <<<625, 256, 0, stream>>>(aggrV, Mtm, h1);
  k_out       <<<628, 256, 0, stream>>>(h1, x, perm, boff, Wa, ba, Wo, bo, out);
}

// Round 7
// 423.032 us; speedup vs baseline: 2.1863x; 1.1718x over previous
//
#include <hip/hip_runtime.h>
#include <hip/hip_bf16.h>
#include <math.h>

#define NN 20000
#define NE 320000
#define DD 256
#define NH 8
#define KK 32
#define NR 5
#define NC 16

typedef unsigned short u16;
typedef unsigned int u32;
typedef __attribute__((ext_vector_type(8))) short bf16x8;
typedef __attribute__((ext_vector_type(4))) float f32x4;

__device__ __forceinline__ float bf2f(u16 v){ return __uint_as_float(((u32)v)<<16); }
__device__ __forceinline__ u16 f2bf(float f){
  u32 u = __float_as_uint(f);
  return (u16)((u + 0x7FFFu + ((u>>16)&1u)) >> 16);
}

// ---------------- node bucketing by type (for typed GEMMs) ----------------
// wave-aggregated: ONE atomic per wave per type.
__global__ void k_nb_count(const int* __restrict__ ntype, int* __restrict__ cnt){
  int n = blockIdx.x*256 + threadIdx.x;
  int t = (n < NN) ? ntype[n] : -1;
  int lane = threadIdx.x & 63;
  #pragma unroll
  for(int tt=0; tt<3; tt++){
    unsigned long long mask = __ballot(t == tt);
    int leader = __ffsll((long long)mask) - 1;
    if(lane == leader) atomicAdd(&cnt[tt], __popcll(mask));
  }
}
__global__ void k_nb_off(const int* __restrict__ cnt, int* __restrict__ boff){
  int a = (cnt[0]+31)&~31;
  int b = (cnt[1]+31)&~31;
  boff[0]=0; boff[1]=a; boff[2]=a+b;
}
__global__ void k_nb_scatter(const int* __restrict__ ntype, const int* __restrict__ boff,
                             int* __restrict__ bcur, int* __restrict__ perm){
  int n = blockIdx.x*256 + threadIdx.x;
  int t = (n < NN) ? ntype[n] : -1;
  int lane = threadIdx.x & 63;
  #pragma unroll
  for(int tt=0; tt<3; tt++){
    unsigned long long mask = __ballot(t == tt);
    if(t == tt){
      int rank = __popcll(mask & ((1ull<<lane)-1ull));
      int leader = __ffsll((long long)mask) - 1;
      int base = 0;
      if(lane == leader) base = atomicAdd(&bcur[tt], __popcll(mask));
      base = __shfl(base, leader);
      perm[boff[tt] + base + rank] = n;
    }
  }
}

// ---------------- CSR by dst ----------------
__global__ void k_deg(const int* __restrict__ ei, int* __restrict__ deg){
  int e = blockIdx.x*256 + threadIdx.x;
  if(e < NE) atomicAdd(&deg[ei[NE + e]], 1);
}
__global__ void k_scan(const int* __restrict__ deg, int* __restrict__ row_off){
  __shared__ int sums[1024];
  int t = threadIdx.x;
  const int CH = 20;                 // 1024*20 >= NN
  int local[CH];
  int s = 0;
  #pragma unroll
  for(int j=0;j<CH;j++){
    int i = t*CH + j;
    local[j] = s;
    s += (i < NN) ? deg[i] : 0;
  }
  sums[t] = s;
  __syncthreads();
  for(int off=1; off<1024; off<<=1){
    int v = (t>=off) ? sums[t-off] : 0;
    __syncthreads();
    if(t>=off) sums[t] += v;
    __syncthreads();
  }
  int base = (t==0) ? 0 : sums[t-1];
  #pragma unroll
  for(int j=0;j<CH;j++){
    int i = t*CH + j;
    if(i < NN) row_off[i] = base + local[j];
  }
  if(t==1023) row_off[NN] = sums[1023];
}
__global__ void k_escatter(const int* __restrict__ ei, const int* __restrict__ etype,
                           const int* __restrict__ row_off, int* __restrict__ cursor,
                           int* __restrict__ packed){
  int e = blockIdx.x*256 + threadIdx.x;
  if(e < NE){
    int dst = ei[NE+e];
    int pos = row_off[dst] + atomicAdd(&cursor[dst],1);
    packed[pos] = ei[e] | (etype[e] << 20);   // src < 2^20, r in bits 20..22
  }
}

// ---------------- prep: cast x -> bf16 ----------------
__global__ void k_castx(const float* __restrict__ x, u16* __restrict__ xb){
  int i = blockIdx.x*256 + threadIdx.x;     // 8 floats per thread; 2500 blocks
  float4 v0 = ((const float4*)x)[i*2+0];
  float4 v1 = ((const float4*)x)[i*2+1];
  uint4 o;
  o.x = (u32)f2bf(v0.x) | ((u32)f2bf(v0.y)<<16);
  o.y = (u32)f2bf(v0.z) | ((u32)f2bf(v0.w)<<16);
  o.z = (u32)f2bf(v1.x) | ((u32)f2bf(v1.y)<<16);
  o.w = (u32)f2bf(v1.z) | ((u32)f2bf(v1.w)<<16);
  ((uint4*)xb)[i] = o;
}

// ---------------- prep: transpose + cast Wk/Wq/Wv/Wa -> bf16 [t][out][in] ----------------
__global__ __launch_bounds__(256) void k_castw(
  const float* __restrict__ Wk, const float* __restrict__ Wq,
  const float* __restrict__ Wv, const float* __restrict__ Wa,
  u16* __restrict__ Wtk, u16* __restrict__ Wtq,
  u16* __restrict__ Wtv, u16* __restrict__ Wta)
{
  __shared__ float tile[32][33];
  int z = blockIdx.z;                       // 0..11: tensor*3 + t
  int tensor = z/3, t = z%3;
  const float* W = (tensor==0) ? Wk : (tensor==1) ? Wq : (tensor==2) ? Wv : Wa;
  u16* O = (tensor==0) ? Wtk : (tensor==1) ? Wtq : (tensor==2) ? Wtv : Wta;
  int i0 = blockIdx.x*32, j0 = blockIdx.y*32;
  int rr = threadIdx.x>>5, cc = threadIdx.x&31;
  #pragma unroll
  for(int p=0;p<4;p++)
    tile[rr+p*8][cc] = W[t*65536 + (i0+rr+p*8)*256 + j0+cc];
  __syncthreads();
  #pragma unroll
  for(int p=0;p<4;p++)
    O[t*65536 + (j0+rr+p*8)*256 + i0+cc] = f2bf(tile[cc][rr+p*8]);
}

// ---------------- prep: transpose + cast rel_msg [r,h,k,l] -> bf16 [r,h,l,k] ----------
__global__ void k_castm(const float* __restrict__ rmsg, u16* __restrict__ Mtm){
  int idx = blockIdx.x*256 + threadIdx.x;   // 160 blocks, 40960 elems
  int l = idx & 31, k = (idx >> 5) & 31, rh = idx >> 10;
  Mtm[(rh*32 + l)*32 + k] = f2bf(rmsg[idx]);
}

// ---------------- prep: transpose + cast W_out [k,c] -> bf16 Wot[c][k] ----------
__global__ void k_casto(const float* __restrict__ Wo, u16* __restrict__ Wot){
  int idx = blockIdx.x*256 + threadIdx.x;   // 16 blocks, 4096 elems
  int c = idx & 15, k = idx >> 4;
  Wot[c*DD + k] = f2bf(Wo[k*NC + c]);
}

// ---------------- typed K/Q/V projections via MFMA 16x16x32 bf16 ----------------
__global__ __launch_bounds__(256) void k_proj(
    const u16* __restrict__ xb, const int* __restrict__ perm, const int* __restrict__ boff,
    const u16* __restrict__ Wtk, const u16* __restrict__ Wtq, const u16* __restrict__ Wtv,
    const float* __restrict__ bk, const float* __restrict__ bq, const float* __restrict__ bv,
    u16* __restrict__ Kn, float* __restrict__ Qn, u16* __restrict__ Vn)
{
  __shared__ u16 xs[32*DD];
  __shared__ int gids[32];
  int tid = threadIdx.x;
  int ts = blockIdx.x*32;
  int t = (ts >= boff[2]) ? 2 : (ts >= boff[1]) ? 1 : 0;   // boff 32-aligned
  if(tid < 32) gids[tid] = perm[ts + tid];
  __syncthreads();
  #pragma unroll
  for(int it=0; it<4; it++){
    int q = tid + it*256;
    int row = q >> 5, c = q & 31;
    int g = gids[row];
    uint4 v = make_uint4(0,0,0,0);
    if(g >= 0) v = ((const uint4*)(xb + (size_t)g*DD))[c];
    ((uint4*)xs)[q] = v;
  }
  __syncthreads();
  int lane = tid & 63;
  int w = tid >> 6;
  int quad = lane >> 4;
  int l16 = lane & 15;
  f32x4 accK[2][4], accQ[2][4], accV[2][4];
  #pragma unroll
  for(int mt=0;mt<2;mt++)
    #pragma unroll
    for(int nt=0;nt<4;nt++){
      accK[mt][nt]=(f32x4)(0.f); accQ[mt][nt]=(f32x4)(0.f); accV[mt][nt]=(f32x4)(0.f);
    }
  const u16* wkp = Wtk + (size_t)t*65536;
  const u16* wqp = Wtq + (size_t)t*65536;
  const u16* wvp = Wtv + (size_t)t*65536;
  #pragma unroll
  for(int kk=0; kk<8; kk++){
    int kb = kk*32 + quad*8;
    bf16x8 a0 = *(const bf16x8*)(xs + l16*DD + kb);
    bf16x8 a1 = *(const bf16x8*)(xs + (16+l16)*DD + kb);
    #pragma unroll
    for(int nt=0; nt<4; nt++){
      int n = w*64 + nt*16 + l16;
      bf16x8 bK = *(const bf16x8*)(wkp + (size_t)n*DD + kb);
      bf16x8 bQ = *(const bf16x8*)(wqp + (size_t)n*DD + kb);
      bf16x8 bV = *(const bf16x8*)(wvp + (size_t)n*DD + kb);
      accK[0][nt] = __builtin_amdgcn_mfma_f32_16x16x32_bf16(a0, bK, accK[0][nt], 0,0,0);
      accK[1][nt] = __builtin_amdgcn_mfma_f32_16x16x32_bf16(a1, bK, accK[1][nt], 0,0,0);
      accQ[0][nt] = __builtin_amdgcn_mfma_f32_16x16x32_bf16(a0, bQ, accQ[0][nt], 0,0,0);
      accQ[1][nt] = __builtin_amdgcn_mfma_f32_16x16x32_bf16(a1, bQ, accQ[1][nt], 0,0,0);
      accV[0][nt] = __builtin_amdgcn_mfma_f32_16x16x32_bf16(a0, bV, accV[0][nt], 0,0,0);
      accV[1][nt] = __builtin_amdgcn_mfma_f32_16x16x32_bf16(a1, bV, accV[1][nt], 0,0,0);
    }
  }
  #pragma unroll
  for(int nt=0; nt<4; nt++){
    int colg = w*64 + nt*16 + l16;
    float bkv = bk[t*DD+colg], bqv = bq[t*DD+colg], bvv = bv[t*DD+colg];
    #pragma unroll
    for(int mt=0; mt<2; mt++){
      #pragma unroll
      for(int reg=0; reg<4; reg++){
        int row = mt*16 + quad*4 + reg;
        int g = gids[row];
        if(g >= 0){
          Kn[(size_t)g*DD + colg] = f2bf(accK[mt][nt][reg] + bkv);
          Qn[(size_t)g*DD + colg] = accQ[mt][nt][reg] + bqv;
          Vn[(size_t)g*DD + colg] = f2bf(accV[mt][nt][reg] + bvv);
        }
      }
    }
  }
}

// ---------------- QA[n,r,h,k] = (prior/sqrtK) * sum_l A[r,h,k,l]*Qn[n,h,l] ----------------
__global__ __launch_bounds__(256) void k_qa(
    const float* __restrict__ Qn, const float* __restrict__ rel_att,
    const float* __restrict__ rel_prior, u16* __restrict__ QA)
{
  __shared__ float At[NH*KK*33];    // [h][l][k], padded to kill bank conflicts
  __shared__ float qs[16*DD];
  int tid = threadIdx.x;
  int r = blockIdx.y;
  int n0 = blockIdx.x * 16;
  const float* A = rel_att + r*NH*KK*KK;
  #pragma unroll
  for(int it=0; it<32; it++){
    int idx = tid + it*256;
    int h = idx >> 10, k = (idx >> 5) & 31, l = idx & 31;
    At[(h*KK + l)*33 + k] = A[idx];
  }
  #pragma unroll
  for(int it=0; it<4; it++){
    int f4 = tid + it*256;
    ((float4*)qs)[f4] = ((const float4*)(Qn + (size_t)n0*DD))[f4];
  }
  __syncthreads();
  int h = tid >> 5, k = tid & 31;
  float areg[KK];
  #pragma unroll
  for(int l=0;l<KK;l++) areg[l] = At[(h*KK + l)*33 + k];
  float scale = rel_prior[r*NH + h] * 0.17677669529663687f;  // 1/sqrt(32)
  for(int n=0;n<16;n++){
    float s = 0.f;
    #pragma unroll
    for(int l4=0;l4<8;l4++){
      float4 q = ((const float4*)(qs + n*DD + h*KK))[l4];
      s += areg[l4*4+0]*q.x + areg[l4*4+1]*q.y + areg[l4*4+2]*q.z + areg[l4*4+3]*q.w;
    }
    QA[((size_t)(n0+n)*NR + r)*DD + tid] = f2bf(s*scale);
  }
}

// ---------------- fused per-node softmax + aggregation (wave per node, no atomics) --------
__global__ __launch_bounds__(256) void k_edge(
    const u16* __restrict__ Kn, const u16* __restrict__ Vn, const u16* __restrict__ QA,
    const int* __restrict__ row_off, const int* __restrict__ packed,
    u16* __restrict__ aggrV)
{
  int lane = threadIdx.x & 63;
  int n = blockIdx.x*4 + (threadIdx.x >> 6);
  if(n >= NN) return;
  int off = lane*4;                  // = h*32 + j*4 with h=lane>>3
  float4 qa0,qa1,qa2,qa3,qa4;
  {
    const u16* qp = QA + (size_t)n*NR*DD + off;
    ushort4 q;
    q = *(const ushort4*)(qp + 0*DD); qa0 = make_float4(bf2f(q.x),bf2f(q.y),bf2f(q.z),bf2f(q.w));
    q = *(const ushort4*)(qp + 1*DD); qa1 = make_float4(bf2f(q.x),bf2f(q.y),bf2f(q.z),bf2f(q.w));
    q = *(const ushort4*)(qp + 2*DD); qa2 = make_float4(bf2f(q.x),bf2f(q.y),bf2f(q.z),bf2f(q.w));
    q = *(const ushort4*)(qp + 3*DD); qa3 = make_float4(bf2f(q.x),bf2f(q.y),bf2f(q.z),bf2f(q.w));
    q = *(const ushort4*)(qp + 4*DD); qa4 = make_float4(bf2f(q.x),bf2f(q.y),bf2f(q.z),bf2f(q.w));
  }
  float4 a0=make_float4(0,0,0,0), a1=a0, a2=a0, a3=a0, a4=a0;
  float s = 0.f;
  int e0 = row_off[n], e1 = row_off[n+1];
  for(int e=e0; e<e1; e++){
    int pk = packed[e];              // wave-uniform
    int src = pk & 0xFFFFF;
    int r = pk >> 20;
    ushort4 ku = *(const ushort4*)(Kn + (size_t)src*DD + off);
    ushort4 vu = *(const ushort4*)(Vn + (size_t)src*DD + off);
    float4 kv = make_float4(bf2f(ku.x),bf2f(ku.y),bf2f(ku.z),bf2f(ku.w));
    float4 vv = make_float4(bf2f(vu.x),bf2f(vu.y),bf2f(vu.z),bf2f(vu.w));
    float4 q;
    switch(r){ case 0: q=qa0; break; case 1: q=qa1; break; case 2: q=qa2; break;
               case 3: q=qa3; break; default: q=qa4; }
    float d = kv.x*q.x + kv.y*q.y + kv.z*q.z + kv.w*q.w;
    d += __shfl_xor(d, 1);           // butterfly within the 8-lane head group
    d += __shfl_xor(d, 2);
    d += __shfl_xor(d, 4);
    float p = __expf(d);             // no max-subtract: logits ~O(1), fp32-safe
    s += p;
    switch(r){
      case 0: a0.x+=p*vv.x; a0.y+=p*vv.y; a0.z+=p*vv.z; a0.w+=p*vv.w; break;
      case 1: a1.x+=p*vv.x; a1.y+=p*vv.y; a1.z+=p*vv.z; a1.w+=p*vv.w; break;
      case 2: a2.x+=p*vv.x; a2.y+=p*vv.y; a2.z+=p*vv.z; a2.w+=p*vv.w; break;
      case 3: a3.x+=p*vv.x; a3.y+=p*vv.y; a3.z+=p*vv.z; a3.w+=p*vv.w; break;
      default:a4.x+=p*vv.x; a4.y+=p*vv.y; a4.z+=p*vv.z; a4.w+=p*vv.w; break;
    }
  }
  float inv = (s > 0.f) ? (1.f/s) : 0.f;
  u16* op = aggrV + (size_t)n*NR*DD + off;
  #define ST(ptr, a) { ushort4 o; o.x=f2bf((a).x*inv); o.y=f2bf((a).y*inv); \
                       o.z=f2bf((a).z*inv); o.w=f2bf((a).w*inv); *(ushort4*)(ptr)=o; }
  ST(op + 0*DD, a0); ST(op + 1*DD, a1); ST(op + 2*DD, a2); ST(op + 3*DD, a3); ST(op + 4*DD, a4);
  #undef ST
}

// ---------------- apply rel_msg per (node, r) via MFMA, sum over r, ELU -> bf16 ----------
#define VSP 264   // padded node row (bf16): 256 + 8 -> 2-way LDS aliasing only (free)
__global__ __launch_bounds__(256) void k_msg(
    const u16* __restrict__ aggrV, const u16* __restrict__ Mtm,
    u16* __restrict__ h1b)
{
  __shared__ u16 Vs[32*VSP];
  int tid = threadIdx.x;
  int n0 = blockIdx.x*32;
  int lane = tid & 63;
  int w = tid >> 6;
  int quad = lane >> 4;
  int l16 = lane & 15;
  f32x4 acc[2][2][2];   // [head][mtile][ntile]
  #pragma unroll
  for(int hh=0;hh<2;hh++)
    #pragma unroll
    for(int mt=0;mt<2;mt++)
      #pragma unroll
      for(int nt=0;nt<2;nt++) acc[hh][mt][nt]=(f32x4)(0.f);
  for(int r=0;r<NR;r++){
    __syncthreads();
    #pragma unroll
    for(int it=0; it<4; it++){
      int q = tid + it*256;
      int row = q >> 5, c = q & 31;
      ((uint4*)(Vs + row*VSP))[c] =
        ((const uint4*)(aggrV + ((size_t)(n0+row)*NR + r)*DD))[c];
    }
    __syncthreads();
    #pragma unroll
    for(int hh=0; hh<2; hh++){
      int h = w*2 + hh;
      bf16x8 a0 = *(const bf16x8*)(Vs + l16*VSP + h*32 + quad*8);
      bf16x8 a1 = *(const bf16x8*)(Vs + (16+l16)*VSP + h*32 + quad*8);
      const u16* mp = Mtm + ((size_t)(r*NH + h)*32)*32;
      bf16x8 b0 = *(const bf16x8*)(mp + l16*32 + quad*8);
      bf16x8 b1 = *(const bf16x8*)(mp + (16+l16)*32 + quad*8);
      acc[hh][0][0] = __builtin_amdgcn_mfma_f32_16x16x32_bf16(a0, b0, acc[hh][0][0], 0,0,0);
      acc[hh][0][1] = __builtin_amdgcn_mfma_f32_16x16x32_bf16(a0, b1, acc[hh][0][1], 0,0,0);
      acc[hh][1][0] = __builtin_amdgcn_mfma_f32_16x16x32_bf16(a1, b0, acc[hh][1][0], 0,0,0);
      acc[hh][1][1] = __builtin_amdgcn_mfma_f32_16x16x32_bf16(a1, b1, acc[hh][1][1], 0,0,0);
    }
  }
  #pragma unroll
  for(int hh=0; hh<2; hh++){
    int h = w*2 + hh;
    #pragma unroll
    for(int mt=0; mt<2; mt++){
      #pragma unroll
      for(int nt=0; nt<2; nt++){
        #pragma unroll
        for(int reg=0; reg<4; reg++){
          int n = n0 + mt*16 + quad*4 + reg;
          float v = acc[hh][mt][nt][reg];
          v = (v > 0.f) ? v : expm1f(v);
          h1b[(size_t)n*DD + h*32 + nt*16 + l16] = f2bf(v);
        }
      }
    }
  }
}

// ---------------- typed Wa (MFMA) + residual + classifier (MFMA) + log_softmax ------------
__global__ __launch_bounds__(256) void k_out(
    const u16* __restrict__ h1b, const float* __restrict__ x,
    const int* __restrict__ perm, const int* __restrict__ boff,
    const u16* __restrict__ Wta, const float* __restrict__ ba,
    const u16* __restrict__ Wot, const float* __restrict__ bo,
    float* __restrict__ out)
{
  __shared__ u16 hs[32*VSP];    // h1 tile (bf16)
  __shared__ u16 h2s[32*VSP];   // h2 tile (bf16) for classifier A-fragments
  __shared__ int gids[32];
  int tid = threadIdx.x;
  int ts = blockIdx.x*32;
  int t = (ts >= boff[2]) ? 2 : (ts >= boff[1]) ? 1 : 0;
  if(tid < 32) gids[tid] = perm[ts + tid];
  __syncthreads();
  #pragma unroll
  for(int it=0; it<4; it++){
    int q = tid + it*256;
    int row = q >> 5, c = q & 31;
    int g = gids[row];
    uint4 v = make_uint4(0,0,0,0);
    if(g >= 0) v = ((const uint4*)(h1b + (size_t)g*DD))[c];
    ((uint4*)(hs + row*VSP))[c] = v;
  }
  __syncthreads();
  int lane = tid & 63, w = tid >> 6, quad = lane >> 4, l16 = lane & 15;
  f32x4 acc[2][4];
  #pragma unroll
  for(int mt=0;mt<2;mt++)
    #pragma unroll
    for(int nt=0;nt<4;nt++) acc[mt][nt]=(f32x4)(0.f);
  const u16* wap = Wta + (size_t)t*65536;
  #pragma unroll
  for(int kk=0; kk<8; kk++){
    int kb = kk*32 + quad*8;
    bf16x8 a0 = *(const bf16x8*)(hs + l16*VSP + kb);
    bf16x8 a1 = *(const bf16x8*)(hs + (16+l16)*VSP + kb);
    #pragma unroll
    for(int nt=0; nt<4; nt++){
      int n = w*64 + nt*16 + l16;
      bf16x8 b = *(const bf16x8*)(wap + (size_t)n*DD + kb);
      acc[0][nt] = __builtin_amdgcn_mfma_f32_16x16x32_bf16(a0, b, acc[0][nt], 0,0,0);
      acc[1][nt] = __builtin_amdgcn_mfma_f32_16x16x32_bf16(a1, b, acc[1][nt], 0,0,0);
    }
  }
  // epilogue: + bias + fp32 residual; h2 -> LDS as bf16
  #pragma unroll
  for(int nt=0; nt<4; nt++){
    int colg = w*64 + nt*16 + l16;
    float bav = ba[t*DD + colg];
    #pragma unroll
    for(int mt=0; mt<2; mt++){
      #pragma unroll
      for(int reg=0; reg<4; reg++){
        int row = mt*16 + quad*4 + reg;
        int g = gids[row];
        float xr = (g>=0) ? x[(size_t)g*DD + colg] : 0.f;
        h2s[row*VSP + colg] = f2bf(acc[mt][nt][reg] + bav + xr);
      }
    }
  }
  __syncthreads();
  // classifier: waves 0,1 each take one m-tile of 16 nodes; N=16 classes = one n-tile
  if(w < 2){
    f32x4 cacc = (f32x4)(0.f);
    #pragma unroll
    for(int kk=0; kk<8; kk++){
      int kb = kk*32 + quad*8;
      bf16x8 a = *(const bf16x8*)(h2s + (w*16 + l16)*VSP + kb);
      bf16x8 b = *(const bf16x8*)(Wot + (size_t)l16*DD + kb);
      cacc = __builtin_amdgcn_mfma_f32_16x16x32_bf16(a, b, cacc, 0,0,0);
    }
    float bov = bo[l16];
    #pragma unroll
    for(int reg=0; reg<4; reg++){
      int row = w*16 + quad*4 + reg;
      int g = gids[row];
      float v = cacc[reg] + bov;     // col = l16 = class
      float m = v;
      m = fmaxf(m, __shfl_xor(m,1)); m = fmaxf(m, __shfl_xor(m,2));
      m = fmaxf(m, __shfl_xor(m,4)); m = fmaxf(m, __shfl_xor(m,8));
      float p = __expf(v - m);
      p += __shfl_xor(p,1); p += __shfl_xor(p,2);
      p += __shfl_xor(p,4); p += __shfl_xor(p,8);
      float lse = m + __logf(p);
      if(g >= 0) out[(size_t)g*NC + l16] = v - lse;
    }
  }
}

extern "C" void kernel_launch(void* const* d_in, const int* in_sizes, int n_in,
                              void* d_out, int out_size, void* d_ws, size_t ws_size,
                              hipStream_t stream)
{
  const float* x     = (const float*)d_in[0];
  const int*   ei    = (const int*)d_in[1];
  const int*   ntype = (const int*)d_in[2];
  const int*   etype = (const int*)d_in[3];
  const float* Wk    = (const float*)d_in[4];
  const float* bk    = (const float*)d_in[5];
  const float* Wq    = (const float*)d_in[6];
  const float* bq    = (const float*)d_in[7];
  const float* Wv    = (const float*)d_in[8];
  const float* bv    = (const float*)d_in[9];
  const float* Wa    = (const float*)d_in[10];
  const float* ba    = (const float*)d_in[11];
  const float* prior = (const float*)d_in[12];
  const float* ratt  = (const float*)d_in[13];
  const float* rmsg  = (const float*)d_in[14];
  const float* Wo    = (const float*)d_in[15];
  const float* bo    = (const float*)d_in[16];
  float* out = (float*)d_out;

  char* ws = (char*)d_ws;
  int* iw      = (int*)ws;
  int* cnt     = iw + 0;
  int* bcur    = iw + 4;
  int* boff    = iw + 8;
  int* deg     = iw + 16;
  int* cursor  = iw + 16 + NN;
  int* row_off = iw + 16 + 2*NN;          // NN+1 entries
  int* perm    = iw + 60032;              // 628*32 = 20096 entries
  int* packed  = iw + 80128;              // NE entries; ends at int 400128

  size_t fb = 1600512;                    // bytes (400128 ints), 256-aligned
  float* Qn    = (float*)(ws + fb); fb += 4ull*NN*DD;
  char*  h1reg = (char*)(ws + fb);  fb += 4ull*NN*DD;   // 20.48 MB region, subdivided below
  u16*   Kn    = (u16*)(ws + fb);   fb += 2ull*NN*DD;
  u16*   Vn    = (u16*)(ws + fb);   fb += 2ull*NN*DD;
  u16*   QA    = (u16*)(ws + fb);   fb += 2ull*NN*NR*DD;
  u16*   aggrV = (u16*)(ws + fb);   fb += 2ull*NN*NR*DD;
  // h1reg subdivision (20.48 MB):
  //   [0 .. 10.24 MB)   : Wtk/Wtq/Wtv (1.18 MB, dead after k_proj), then h1b (10.24 MB, k_msg)
  //   [11 MB .. 11.4 MB): Wta (393 KB) + Wot (8 KB) — written k_castw/k_casto, read k_out only
  u16* Wtk = (u16*)h1reg;
  u16* Wtq = Wtk + 3*65536;
  u16* Wtv = Wtq + 3*65536;
  u16* h1b = (u16*)h1reg;                 // overwrites Wt* (dead) at k_msg time
  u16* Wta = (u16*)(h1reg + 11534336);    // +11 MB
  u16* Wot = Wta + 3*65536;
  u16* xb  = aggrV;                       // NN*DD bf16, dead until k_edge
  u16* Mtm = (u16*)(iw + 16);             // 80 KB in deg/cursor ints (dead after k_escatter)

  hipMemsetAsync(iw, 0, (size_t)(16 + 2*NN)*sizeof(int), stream);      // cnt,bcur,boff,deg,cursor
  hipMemsetAsync(perm, 0xFF, (size_t)20096*sizeof(int), stream);       // perm = -1

  k_nb_count  <<<79, 256, 0, stream>>>(ntype, cnt);
  k_nb_off    <<<1, 1, 0, stream>>>(cnt, boff);
  k_nb_scatter<<<79, 256, 0, stream>>>(ntype, boff, bcur, perm);
  k_deg       <<<1250, 256, 0, stream>>>(ei, deg);
  k_scan      <<<1, 1024, 0, stream>>>(deg, row_off);
  k_escatter  <<<1250, 256, 0, stream>>>(ei, etype, row_off, cursor, packed);
  k_castm     <<<160, 256, 0, stream>>>(rmsg, Mtm);   // after k_escatter: reuses deg/cursor ints
  k_castx     <<<2500, 256, 0, stream>>>(x, xb);
  k_castw     <<<dim3(8,8,12), 256, 0, stream>>>(Wk, Wq, Wv, Wa, Wtk, Wtq, Wtv, Wta);
  k_casto     <<<16, 256, 0, stream>>>(Wo, Wot);
  k_proj      <<<628, 256, 0, stream>>>(xb, perm, boff, Wtk, Wtq, Wtv, bk, bq, bv, Kn, Qn, Vn);
  k_qa        <<<dim3(1250,5), 256, 0, stream>>>(Qn, ratt, prior, QA);
  k_edge      <<<5000, 256, 0, stream>>>(Kn, Vn, QA, row_off, packed, aggrV);
  k_msg       <<<625, 256, 0, stream>>>(aggrV, Mtm, h1b);
  k_out       <<<628, 256, 0, stream>>>(h1b, x, perm, boff, Wta, ba, Wot, bo, out);
}